// Round 3
// baseline (728.636 us; speedup 1.0000x reference)
//
#include <hip/hip_runtime.h>
#include <math.h>

typedef __bf16 bf16;
typedef __bf16 bf16x8 __attribute__((ext_vector_type(8)));
typedef float  f32x4  __attribute__((ext_vector_type(4)));

#define B_   4
#define N_   2048
#define C_   768
#define H_   12
#define T_   8192      // B_*N_
#define HID_ 3072

// ---------------------------------------------------------------------------
// LayerNorm: one wave per row (C=768 = 12*64). f32 in, fp32 stats, bf16 out.
// ---------------------------------------------------------------------------
__global__ __launch_bounds__(256)
void ln_kernel(const float* __restrict__ inp, const float* __restrict__ g,
               const float* __restrict__ bsh, bf16* __restrict__ out)
{
    int wave = threadIdx.x >> 6, lane = threadIdx.x & 63;
    long long row = (long long)blockIdx.x * 4 + wave;
    const float* p = inp + row * C_;
    float v[12];
    #pragma unroll
    for (int i = 0; i < 12; i++) v[i] = p[i * 64 + lane];
    float s = 0.f, s2 = 0.f;
    #pragma unroll
    for (int i = 0; i < 12; i++) { s += v[i]; s2 += v[i] * v[i]; }
    #pragma unroll
    for (int m = 1; m < 64; m <<= 1) {
        s  += __shfl_xor(s,  m, 64);
        s2 += __shfl_xor(s2, m, 64);
    }
    float mu  = s  * (1.f / C_);
    float var = s2 * (1.f / C_) - mu * mu;
    float rs  = rsqrtf(var + 1e-5f);
    bf16* o = out + row * C_;
    #pragma unroll
    for (int i = 0; i < 12; i++) {
        int c = i * 64 + lane;
        o[c] = (bf16)(((v[i] - mu) * rs) * g[c] + bsh[c]);
    }
}

// ---------------------------------------------------------------------------
// GEMM: C[M,N] = A[M,K](bf16) @ Bw[N,K](f32)^T (+epilogue). 128x128, BK=32.
// 256 threads = 4 waves (2x2), each wave 64x64 via 4x4 mfma_f32_16x16x32_bf16.
// Bw is converted f32->bf16 during LDS staging.
// MODE 0: out bf16 = acc                      (qkv -> ws)
// MODE 1: out f32  = acc + bias + resid_f     (proj/fc2 + residual; resid may
//         alias out: per-element load-before-store by owner thread only)
// MODE 2: out bf16 = gelu(acc + bias)         (fc1 -> ws)
// ---------------------------------------------------------------------------
template<int MODE>
__global__ __launch_bounds__(256)
void gemm_bt(const bf16* __restrict__ A, const float* __restrict__ Bw,
             int M, int N, int K,
             const float* __restrict__ bias,
             const float* resid_f,
             void* out)
{
    __shared__ bf16 At[128 * 32];
    __shared__ bf16 Bt[128 * 32];
    int tid  = threadIdx.x;
    int lane = tid & 63, wave = tid >> 6;
    int quad = lane >> 4, l15 = lane & 15;
    int bm = blockIdx.x, bn = blockIdx.y;
    int wm = wave >> 1, wn = wave & 1;

    f32x4 acc[4][4];
    f32x4 zero = {0.f, 0.f, 0.f, 0.f};
    #pragma unroll
    for (int mt = 0; mt < 4; mt++)
        #pragma unroll
        for (int nt = 0; nt < 4; nt++) acc[mt][nt] = zero;

    int arow = tid >> 2;          // 0..63
    int akof = (tid & 3) << 3;    // 0,8,16,24
    const bf16*  ag = A  + (size_t)(bm * 128 + arow) * K + akof;
    const float* bg = Bw + (size_t)(bn * 128 + arow) * K + akof;

    for (int k0 = 0; k0 < K; k0 += 32) {
        bf16x8 a0 = *(const bf16x8*)(ag);
        bf16x8 a1 = *(const bf16x8*)(ag + (size_t)64 * K);
        f32x4 b0a = *(const f32x4*)(bg);
        f32x4 b0b = *(const f32x4*)(bg + 4);
        f32x4 b1a = *(const f32x4*)(bg + (size_t)64 * K);
        f32x4 b1b = *(const f32x4*)(bg + (size_t)64 * K + 4);
        bf16x8 b0, b1;
        #pragma unroll
        for (int j = 0; j < 4; j++) {
            b0[j] = (bf16)b0a[j]; b0[4 + j] = (bf16)b0b[j];
            b1[j] = (bf16)b1a[j]; b1[4 + j] = (bf16)b1b[j];
        }
        *(bf16x8*)(&At[arow * 32 + akof])        = a0;
        *(bf16x8*)(&At[(arow + 64) * 32 + akof]) = a1;
        *(bf16x8*)(&Bt[arow * 32 + akof])        = b0;
        *(bf16x8*)(&Bt[(arow + 64) * 32 + akof]) = b1;
        ag += 32; bg += 32;
        __syncthreads();

        bf16x8 af[4], bfr[4];
        #pragma unroll
        for (int mt = 0; mt < 4; mt++)
            af[mt] = *(const bf16x8*)(&At[(wm * 64 + mt * 16 + l15) * 32 + quad * 8]);
        #pragma unroll
        for (int nt = 0; nt < 4; nt++)
            bfr[nt] = *(const bf16x8*)(&Bt[(wn * 64 + nt * 16 + l15) * 32 + quad * 8]);
        #pragma unroll
        for (int mt = 0; mt < 4; mt++)
            #pragma unroll
            for (int nt = 0; nt < 4; nt++)
                acc[mt][nt] = __builtin_amdgcn_mfma_f32_16x16x32_bf16(
                    af[mt], bfr[nt], acc[mt][nt], 0, 0, 0);
        __syncthreads();
    }

    // epilogue: C row = quad*4 + r, col = l15 (within each 16x16 tile)
    #pragma unroll
    for (int nt = 0; nt < 4; nt++) {
        int col = bn * 128 + wn * 64 + nt * 16 + l15;
        float bv = (MODE == 0) ? 0.f : bias[col];
        #pragma unroll
        for (int mt = 0; mt < 4; mt++) {
            #pragma unroll
            for (int r = 0; r < 4; r++) {
                int row = bm * 128 + wm * 64 + mt * 16 + quad * 4 + r;
                size_t idx = (size_t)row * N + col;
                float v = acc[mt][nt][r] + bv;
                if (MODE == 0) {
                    ((bf16*)out)[idx] = (bf16)v;
                } else if (MODE == 1) {
                    ((float*)out)[idx] = v + resid_f[idx];
                } else {
                    float ge = 0.5f * v * (1.f + erff(v * 0.70710678118f));
                    ((bf16*)out)[idx] = (bf16)ge;
                }
            }
        }
    }
}

// ---------------------------------------------------------------------------
// Flash attention. qkv (bf16, ws) layout: [T, 3*C], q|k|v at col 0/768/1536,
// head h at +h*64. One block = (b, h, 64-query tile); 4 waves x 16 queries.
// K/V tiles of 64 keys staged in LDS; online softmax; P via LDS to A-layout.
// ---------------------------------------------------------------------------
__global__ __launch_bounds__(256)
void attn_kernel(const bf16* __restrict__ qkv, bf16* __restrict__ o)
{
    __shared__ bf16 Kt[64 * 64];
    __shared__ bf16 Vt[64 * 64];
    __shared__ bf16 Pt[4][16 * 64];

    int tid = threadIdx.x, lane = tid & 63, wave = tid >> 6;
    int quad = lane >> 4, l15 = lane & 15;
    int blk = blockIdx.x;
    int qt = blk & 31;      // 32 query tiles of 64
    int bh = blk >> 5;      // 0..47
    int b = bh / H_, h = bh % H_;

    const size_t rs = 3 * C_;   // 2304
    const bf16* qbase = qkv + (size_t)(b * N_) * rs + h * 64;
    const bf16* kbase = qbase + C_;
    const bf16* vbase = qbase + 2 * C_;

    // Q fragments (A-layout), resident all kernel
    bf16x8 qa[2];
    {
        int m = qt * 64 + wave * 16 + l15;
        const bf16* qp = qbase + (size_t)m * rs + quad * 8;
        qa[0] = *(const bf16x8*)(qp);
        qa[1] = *(const bf16x8*)(qp + 32);
    }

    f32x4 oacc[4];
    f32x4 zero = {0.f, 0.f, 0.f, 0.f};
    #pragma unroll
    for (int nt = 0; nt < 4; nt++) oacc[nt] = zero;
    float mrun[4], lrun[4];
    #pragma unroll
    for (int r = 0; r < 4; r++) { mrun[r] = -1e30f; lrun[r] = 0.f; }

    int srow = tid >> 3;           // 0..31
    int sofs = (tid & 7) << 3;     // 0..56

    for (int kt = 0; kt < 32; kt++) {
        const bf16* kg = kbase + (size_t)(kt * 64 + srow) * rs + sofs;
        const bf16* vg = vbase + (size_t)(kt * 64 + srow) * rs + sofs;
        *(bf16x8*)(&Kt[srow * 64 + sofs])        = *(const bf16x8*)(kg);
        *(bf16x8*)(&Kt[(srow + 32) * 64 + sofs]) = *(const bf16x8*)(kg + 32 * rs);
        *(bf16x8*)(&Vt[srow * 64 + sofs])        = *(const bf16x8*)(vg);
        *(bf16x8*)(&Vt[(srow + 32) * 64 + sofs]) = *(const bf16x8*)(vg + 32 * rs);
        __syncthreads();

        // S = Q K^T  (rows=queries, cols=keys), 4 key sub-tiles of 16
        f32x4 s[4];
        #pragma unroll
        for (int nt = 0; nt < 4; nt++) {
            bf16x8 kb0 = *(const bf16x8*)(&Kt[(nt * 16 + l15) * 64 + quad * 8]);
            bf16x8 kb1 = *(const bf16x8*)(&Kt[(nt * 16 + l15) * 64 + 32 + quad * 8]);
            f32x4 sv = zero;
            sv = __builtin_amdgcn_mfma_f32_16x16x32_bf16(qa[0], kb0, sv, 0, 0, 0);
            sv = __builtin_amdgcn_mfma_f32_16x16x32_bf16(qa[1], kb1, sv, 0, 0, 0);
            s[nt] = sv;
        }

        // online softmax (scale 1/8 folded in)
        float tmax[4];
        #pragma unroll
        for (int r = 0; r < 4; r++)
            tmax[r] = fmaxf(fmaxf(s[0][r], s[1][r]), fmaxf(s[2][r], s[3][r]));
        #pragma unroll
        for (int m = 1; m < 16; m <<= 1)
            #pragma unroll
            for (int r = 0; r < 4; r++)
                tmax[r] = fmaxf(tmax[r], __shfl_xor(tmax[r], m, 64));

        float p[4][4], alpha[4], psum[4];
        #pragma unroll
        for (int r = 0; r < 4; r++) {
            float mnew = fmaxf(mrun[r], tmax[r] * 0.125f);
            alpha[r] = expf(mrun[r] - mnew);
            mrun[r] = mnew;
            float ps = 0.f;
            #pragma unroll
            for (int nt = 0; nt < 4; nt++) {
                float pv = expf(s[nt][r] * 0.125f - mnew);
                p[nt][r] = pv;
                ps += pv;
            }
            psum[r] = ps;
        }
        #pragma unroll
        for (int m = 1; m < 16; m <<= 1)
            #pragma unroll
            for (int r = 0; r < 4; r++)
                psum[r] += __shfl_xor(psum[r], m, 64);
        #pragma unroll
        for (int r = 0; r < 4; r++) lrun[r] = lrun[r] * alpha[r] + psum[r];
        #pragma unroll
        for (int nt = 0; nt < 4; nt++)
            #pragma unroll
            for (int r = 0; r < 4; r++) oacc[nt][r] *= alpha[r];

        // P (C-layout) -> LDS -> A-layout
        bf16* pw = &Pt[wave][0];
        #pragma unroll
        for (int nt = 0; nt < 4; nt++)
            #pragma unroll
            for (int r = 0; r < 4; r++)
                pw[(quad * 4 + r) * 64 + nt * 16 + l15] = (bf16)p[nt][r];
        __syncthreads();   // insurance: order P write vs cross-lane P read

        // O += P @ V   (K=64 keys in 2 chunks of 32)
        #pragma unroll
        for (int kc = 0; kc < 2; kc++) {
            bf16x8 pa = *(const bf16x8*)(&pw[l15 * 64 + kc * 32 + quad * 8]);
            #pragma unroll
            for (int nt = 0; nt < 4; nt++) {
                bf16x8 vb;
                #pragma unroll
                for (int j = 0; j < 8; j++)
                    vb[j] = Vt[(kc * 32 + quad * 8 + j) * 64 + nt * 16 + l15];
                oacc[nt] = __builtin_amdgcn_mfma_f32_16x16x32_bf16(
                    pa, vb, oacc[nt], 0, 0, 0);
            }
        }
        __syncthreads();
    }

    // write O (bf16) at [b*N + q, h*64 + d]
    int mrow = qt * 64 + wave * 16;
    bf16* ob = o + (size_t)(b * N_ + mrow) * C_ + h * 64;
    #pragma unroll
    for (int nt = 0; nt < 4; nt++)
        #pragma unroll
        for (int r = 0; r < 4; r++) {
            float v = oacc[nt][r] / lrun[r];
            ob[(size_t)(quad * 4 + r) * C_ + nt * 16 + l15] = (bf16)v;
        }
}

// ---------------------------------------------------------------------------
// Inputs/outputs are FLOAT32 (per the reference's jnp.float32 and the harness
// contract). Internal compute: bf16 MFMA; residual stream f32 in d_out.
// Workspace (<= 63 MB):
//   R0 [0, 50331648)        : qkv [T,2304] bf16 -> later gelu(fc1) [T,3072] bf16
//   R1 [50331648, 62914560) : h / o / h2 [T,768] bf16
// ---------------------------------------------------------------------------
extern "C" void kernel_launch(void* const* d_in, const int* in_sizes, int n_in,
                              void* d_out, int out_size, void* d_ws, size_t ws_size,
                              hipStream_t stream)
{
    const float* x      = (const float*)d_in[0];
    const float* ln1_g  = (const float*)d_in[1];
    const float* ln1_b  = (const float*)d_in[2];
    const float* qkv_w  = (const float*)d_in[3];
    const float* proj_w = (const float*)d_in[4];
    const float* proj_b = (const float*)d_in[5];
    const float* ln2_g  = (const float*)d_in[6];
    const float* ln2_b  = (const float*)d_in[7];
    const float* fc1_w  = (const float*)d_in[8];
    const float* fc1_b  = (const float*)d_in[9];
    const float* fc2_w  = (const float*)d_in[10];
    const float* fc2_b  = (const float*)d_in[11];
    float* out = (float*)d_out;

    char* ws = (char*)d_ws;
    bf16* R0 = (bf16*)ws;                                   // T x 2304 then T x 3072
    bf16* R1 = (bf16*)(ws + (size_t)T_ * HID_ * 2);         // T x 768

    // 1. LN1: x (f32) -> h (R1, bf16)
    ln_kernel<<<T_ / 4, 256, 0, stream>>>(x, ln1_g, ln1_b, R1);
    // 2. qkv = h @ qkv_w^T -> R0 [T,2304] bf16
    gemm_bt<0><<<dim3(T_ / 128, 2304 / 128), 256, 0, stream>>>(
        R1, qkv_w, T_, 2304, C_, nullptr, nullptr, R0);
    // 3. attention -> o (R1) [T,768] bf16
    attn_kernel<<<48 * 32, 256, 0, stream>>>(R0, R1);
    // 4. x1 = x + o @ proj_w^T + proj_b -> d_out (f32)
    gemm_bt<1><<<dim3(T_ / 128, C_ / 128), 256, 0, stream>>>(
        R1, proj_w, T_, C_, C_, proj_b, x, out);
    // 5. LN2: x1 (f32) -> h2 (R1, bf16)
    ln_kernel<<<T_ / 4, 256, 0, stream>>>(out, ln2_g, ln2_b, R1);
    // 6. g1 = gelu(h2 @ fc1_w^T + fc1_b) -> R0 [T,3072] bf16
    gemm_bt<2><<<dim3(T_ / 128, HID_ / 128), 256, 0, stream>>>(
        R1, fc1_w, T_, HID_, C_, fc1_b, nullptr, R0);
    // 7. out = x1 + g1 @ fc2_w^T + fc2_b -> d_out (in-place residual read, f32)
    gemm_bt<1><<<dim3(T_ / 128, C_ / 128), 256, 0, stream>>>(
        R0, fc2_w, T_, C_, HID_, fc2_b, out, out);
}

// Round 4
// 655.936 us; speedup vs baseline: 1.1108x; 1.1108x over previous
//
#include <hip/hip_runtime.h>
#include <math.h>

typedef __bf16 bf16;
typedef __bf16 bf16x4 __attribute__((ext_vector_type(4)));
typedef __bf16 bf16x8 __attribute__((ext_vector_type(8)));
typedef float  f32x4  __attribute__((ext_vector_type(4)));

#define B_   4
#define N_   2048
#define C_   768
#define H_   12
#define T_   8192      // B_*N_
#define HID_ 3072

// async global->LDS, 16 B per lane. LDS dest must be wave-uniform base + lane*16.
typedef const __attribute__((address_space(1))) unsigned int* as1_u32;
typedef __attribute__((address_space(3))) unsigned int* as3_u32;
__device__ __forceinline__ void gl_lds16(const void* g, void* l) {
    __builtin_amdgcn_global_load_lds((as1_u32)g, (as3_u32)l, 16, 0, 0);
}

// ---------------------------------------------------------------------------
// LayerNorm: one wave per row (C=768 = 12*64). f32 in, fp32 stats, bf16 out.
// ---------------------------------------------------------------------------
__global__ __launch_bounds__(256)
void ln_kernel(const float* __restrict__ inp, const float* __restrict__ g,
               const float* __restrict__ bsh, bf16* __restrict__ out)
{
    int wave = threadIdx.x >> 6, lane = threadIdx.x & 63;
    long long row = (long long)blockIdx.x * 4 + wave;
    const float* p = inp + row * C_;
    float v[12];
    #pragma unroll
    for (int i = 0; i < 12; i++) v[i] = p[i * 64 + lane];
    float s = 0.f, s2 = 0.f;
    #pragma unroll
    for (int i = 0; i < 12; i++) { s += v[i]; s2 += v[i] * v[i]; }
    #pragma unroll
    for (int m = 1; m < 64; m <<= 1) {
        s  += __shfl_xor(s,  m, 64);
        s2 += __shfl_xor(s2, m, 64);
    }
    float mu  = s  * (1.f / C_);
    float var = s2 * (1.f / C_) - mu * mu;
    float rs  = rsqrtf(var + 1e-5f);
    bf16* o = out + row * C_;
    #pragma unroll
    for (int i = 0; i < 12; i++) {
        int c = i * 64 + lane;
        o[c] = (bf16)(((v[i] - mu) * rs) * g[c] + bsh[c]);
    }
}

// ---------------------------------------------------------------------------
// GEMM: C[M,N] = A[M,K](bf16) @ Bw[N,K](f32)^T (+epilogue). 128x128, BK=32.
// A staged via global_load_lds(16B); Bw converted f32->bf16 through VGPRs.
// MODE 1: out f32  = acc + bias + resid_f   (proj/fc2 + residual; resid may
//         alias out: per-element load-before-store by owner thread)
// MODE 2: out bf16 = gelu(acc + bias)       (fc1 -> ws)
// MODE 3: qkv split: cols [0,1536) -> out bf16 [row*1536+col] (Q|K packed);
//         cols [1536,2304) -> V transposed into out2[bh][d][n] (bf16),
//         packed 4 tokens per 8B store.
// ---------------------------------------------------------------------------
template<int MODE>
__global__ __launch_bounds__(256)
void gemm_bt(const bf16* __restrict__ A, const float* __restrict__ Bw,
             int M, int N, int K,
             const float* __restrict__ bias,
             const float* resid_f,
             void* out, bf16* out2)
{
    __shared__ bf16 At[128 * 32];
    __shared__ bf16 Bt[128 * 32];
    int tid  = threadIdx.x;
    int lane = tid & 63, wave = tid >> 6;
    int quad = lane >> 4, l15 = lane & 15;
    int bm = blockIdx.x, bn = blockIdx.y;
    int wm = wave >> 1, wn = wave & 1;

    f32x4 acc[4][4];
    f32x4 zero = {0.f, 0.f, 0.f, 0.f};
    #pragma unroll
    for (int mt = 0; mt < 4; mt++)
        #pragma unroll
        for (int nt = 0; nt < 4; nt++) acc[mt][nt] = zero;

    int arow = tid >> 2;          // 0..63
    int akof = (tid & 3) << 3;    // 0,8,16,24  (elements)
    const bf16*  ag = A  + (size_t)(bm * 128 + arow) * K + akof;
    const float* bg = Bw + (size_t)(bn * 128 + arow) * K + akof;

    for (int k0 = 0; k0 < K; k0 += 32) {
        // A: async 16B DMA to LDS; element offset arow*32+akof == tid*8.
        gl_lds16(ag,                    &At[tid * 8]);
        gl_lds16(ag + (size_t)64 * K,   &At[2048 + tid * 8]);
        // B: f32 loads + convert
        f32x4 b0a = *(const f32x4*)(bg);
        f32x4 b0b = *(const f32x4*)(bg + 4);
        f32x4 b1a = *(const f32x4*)(bg + (size_t)64 * K);
        f32x4 b1b = *(const f32x4*)(bg + (size_t)64 * K + 4);
        bf16x8 b0, b1;
        #pragma unroll
        for (int j = 0; j < 4; j++) {
            b0[j] = (bf16)b0a[j]; b0[4 + j] = (bf16)b0b[j];
            b1[j] = (bf16)b1a[j]; b1[4 + j] = (bf16)b1b[j];
        }
        *(bf16x8*)(&Bt[tid * 8])        = b0;
        *(bf16x8*)(&Bt[2048 + tid * 8]) = b1;
        ag += 32; bg += 32;
        __syncthreads();

        bf16x8 af[4], bfr[4];
        #pragma unroll
        for (int mt = 0; mt < 4; mt++)
            af[mt] = *(const bf16x8*)(&At[(wm * 64 + mt * 16 + l15) * 32 + quad * 8]);
        #pragma unroll
        for (int nt = 0; nt < 4; nt++)
            bfr[nt] = *(const bf16x8*)(&Bt[(wn * 64 + nt * 16 + l15) * 32 + quad * 8]);
        #pragma unroll
        for (int mt = 0; mt < 4; mt++)
            #pragma unroll
            for (int nt = 0; nt < 4; nt++)
                acc[mt][nt] = __builtin_amdgcn_mfma_f32_16x16x32_bf16(
                    af[mt], bfr[nt], acc[mt][nt], 0, 0, 0);
        __syncthreads();
    }

    // epilogue: C row = quad*4 + r, col = l15 (within each 16x16 tile)
    if (MODE == 3) {
        if (bn < 12) {
            // Q|K block: row-major, stride 1536
            #pragma unroll
            for (int nt = 0; nt < 4; nt++) {
                int col = bn * 128 + wn * 64 + nt * 16 + l15;
                #pragma unroll
                for (int mt = 0; mt < 4; mt++)
                    #pragma unroll
                    for (int r = 0; r < 4; r++) {
                        int row = bm * 128 + wm * 64 + mt * 16 + quad * 4 + r;
                        ((bf16*)out)[(size_t)row * 1536 + col] = (bf16)acc[mt][nt][r];
                    }
            }
        } else {
            // V block: write transposed V_T[bh][d][n]
            int b = bm >> 4;                       // 2048/128 = 16 tiles per batch
            #pragma unroll
            for (int nt = 0; nt < 4; nt++) {
                int vcol = bn * 128 - 1536 + wn * 64 + nt * 16 + l15;  // 0..767
                int h = vcol >> 6, d = vcol & 63;
                size_t rowbase = ((size_t)(b * H_ + h) * 64 + d) * N_;
                #pragma unroll
                for (int mt = 0; mt < 4; mt++) {
                    int n0 = (bm & 15) * 128 + wm * 64 + mt * 16 + quad * 4;
                    bf16x4 pv;
                    #pragma unroll
                    for (int r = 0; r < 4; r++) pv[r] = (bf16)acc[mt][nt][r];
                    *(bf16x4*)(&out2[rowbase + n0]) = pv;
                }
            }
        }
    } else {
        #pragma unroll
        for (int nt = 0; nt < 4; nt++) {
            int col = bn * 128 + wn * 64 + nt * 16 + l15;
            float bv = bias[col];
            #pragma unroll
            for (int mt = 0; mt < 4; mt++) {
                #pragma unroll
                for (int r = 0; r < 4; r++) {
                    int row = bm * 128 + wm * 64 + mt * 16 + quad * 4 + r;
                    size_t idx = (size_t)row * N + col;
                    float v = acc[mt][nt][r] + bv;
                    if (MODE == 1) {
                        ((float*)out)[idx] = v + resid_f[idx];
                    } else {
                        float ge = 0.5f * v * (1.f + erff(v * 0.70710678118f));
                        ((bf16*)out)[idx] = (bf16)ge;
                    }
                }
            }
        }
    }
}

// ---------------------------------------------------------------------------
// Flash attention. Inputs: qk [T,1536] (Q|K per token, bf16) and
// vt [48][64][2048] (V transposed per head, bf16).
// One block = (b, h, 64-query tile); 4 waves x 16 queries.
// K tile [key][d], V tile [d][key] in LDS -> all MFMA frags are b128 reads.
// ---------------------------------------------------------------------------
__global__ __launch_bounds__(256)
void attn_kernel(const bf16* __restrict__ qk, const bf16* __restrict__ vt,
                 bf16* __restrict__ o)
{
    __shared__ bf16 Kt[64 * 64];        // [key][d]
    __shared__ bf16 Vt[64 * 64];        // [d][key]
    __shared__ bf16 Pt[4][16 * 72];     // per-wave P, padded rows (72)

    int tid = threadIdx.x, lane = tid & 63, wave = tid >> 6;
    int quad = lane >> 4, l15 = lane & 15;
    int blk = blockIdx.x;
    int qt = blk & 31;      // 32 query tiles of 64
    int bh = blk >> 5;      // 0..47
    int b = bh / H_, h = bh % H_;

    const bf16* qbase = qk + (size_t)(b * N_) * 1536 + h * 64;
    const bf16* kbase = qbase + 768;
    const bf16* vtb   = vt + (size_t)(bh * 64) * N_;

    // Q fragments (A-layout), resident all kernel
    bf16x8 qa[2];
    {
        int m = qt * 64 + wave * 16 + l15;
        const bf16* qp = qbase + (size_t)m * 1536 + quad * 8;
        qa[0] = *(const bf16x8*)(qp);
        qa[1] = *(const bf16x8*)(qp + 32);
    }

    f32x4 oacc[4];
    f32x4 zero = {0.f, 0.f, 0.f, 0.f};
    #pragma unroll
    for (int nt = 0; nt < 4; nt++) oacc[nt] = zero;
    float mrun[4], lrun[4];
    #pragma unroll
    for (int r = 0; r < 4; r++) { mrun[r] = -1e30f; lrun[r] = 0.f; }

    int srow = tid >> 3;           // 0..31
    int sofs = (tid & 7) << 3;     // 0..56 elements

    for (int kt = 0; kt < 32; kt++) {
        const bf16* kg = kbase + (size_t)(kt * 64 + srow) * 1536 + sofs;
        const bf16* vg = vtb + (size_t)srow * N_ + kt * 64 + sofs;
        gl_lds16(kg,                 &Kt[tid * 8]);
        gl_lds16(kg + 32 * 1536,     &Kt[2048 + tid * 8]);
        gl_lds16(vg,                 &Vt[tid * 8]);
        gl_lds16(vg + 32 * N_,       &Vt[2048 + tid * 8]);
        __syncthreads();

        // S = Q K^T  (rows=queries, cols=keys), 4 key sub-tiles of 16
        f32x4 s[4];
        #pragma unroll
        for (int nt = 0; nt < 4; nt++) {
            bf16x8 kb0 = *(const bf16x8*)(&Kt[(nt * 16 + l15) * 64 + quad * 8]);
            bf16x8 kb1 = *(const bf16x8*)(&Kt[(nt * 16 + l15) * 64 + 32 + quad * 8]);
            f32x4 sv = zero;
            sv = __builtin_amdgcn_mfma_f32_16x16x32_bf16(qa[0], kb0, sv, 0, 0, 0);
            sv = __builtin_amdgcn_mfma_f32_16x16x32_bf16(qa[1], kb1, sv, 0, 0, 0);
            s[nt] = sv;
        }

        // online softmax (scale 1/8 folded in)
        float tmax[4];
        #pragma unroll
        for (int r = 0; r < 4; r++)
            tmax[r] = fmaxf(fmaxf(s[0][r], s[1][r]), fmaxf(s[2][r], s[3][r]));
        #pragma unroll
        for (int m = 1; m < 16; m <<= 1)
            #pragma unroll
            for (int r = 0; r < 4; r++)
                tmax[r] = fmaxf(tmax[r], __shfl_xor(tmax[r], m, 64));

        float p[4][4], alpha[4], psum[4];
        #pragma unroll
        for (int r = 0; r < 4; r++) {
            float mnew = fmaxf(mrun[r], tmax[r] * 0.125f);
            alpha[r] = __expf(mrun[r] - mnew);
            mrun[r] = mnew;
            float ps = 0.f;
            #pragma unroll
            for (int nt = 0; nt < 4; nt++) {
                float pv = __expf(s[nt][r] * 0.125f - mnew);
                p[nt][r] = pv;
                ps += pv;
            }
            psum[r] = ps;
        }
        #pragma unroll
        for (int m = 1; m < 16; m <<= 1)
            #pragma unroll
            for (int r = 0; r < 4; r++)
                psum[r] += __shfl_xor(psum[r], m, 64);
        #pragma unroll
        for (int r = 0; r < 4; r++) lrun[r] = lrun[r] * alpha[r] + psum[r];
        #pragma unroll
        for (int nt = 0; nt < 4; nt++)
            #pragma unroll
            for (int r = 0; r < 4; r++) oacc[nt][r] *= alpha[r];

        // P (C-layout) -> LDS (padded rows, conflict-reduced) -> A-layout
        bf16* pw = &Pt[wave][0];
        #pragma unroll
        for (int nt = 0; nt < 4; nt++)
            #pragma unroll
            for (int r = 0; r < 4; r++)
                pw[(quad * 4 + r) * 72 + nt * 16 + l15] = (bf16)p[nt][r];
        __syncthreads();   // order P writes vs cross-lane P reads

        // O += P @ V   (K=64 keys in 2 chunks of 32); V B-frags are b128 reads
        #pragma unroll
        for (int kc = 0; kc < 2; kc++) {
            bf16x8 pa = *(const bf16x8*)(&pw[l15 * 72 + kc * 32 + quad * 8]);
            #pragma unroll
            for (int nt = 0; nt < 4; nt++) {
                bf16x8 vb = *(const bf16x8*)(&Vt[(nt * 16 + l15) * 64 + kc * 32 + quad * 8]);
                oacc[nt] = __builtin_amdgcn_mfma_f32_16x16x32_bf16(
                    pa, vb, oacc[nt], 0, 0, 0);
            }
        }
        __syncthreads();
    }

    // write O (bf16) at [b*N + q, h*64 + d]
    int mrow = qt * 64 + wave * 16;
    bf16* ob = o + (size_t)(b * N_ + mrow) * C_ + h * 64;
    #pragma unroll
    for (int nt = 0; nt < 4; nt++)
        #pragma unroll
        for (int r = 0; r < 4; r++) {
            float v = oacc[nt][r] / lrun[r];
            ob[(size_t)(quad * 4 + r) * C_ + nt * 16 + l15] = (bf16)v;
        }
}

// ---------------------------------------------------------------------------
// Workspace (62.9 MB, proven safe in round 3):
//   [0, 25165824)          QK [T,1536] bf16      (attention phase)
//   [25165824, 37748736)   V_T [48][64][2048] bf16
//   [0, 50331648)          gelu(fc1) [T,3072] bf16 (MLP phase, reuses above)
//   [50331648, 62914560)   R1: h / o / h2 [T,768] bf16
// Residual stream x1 lives f32 in d_out.
// ---------------------------------------------------------------------------
extern "C" void kernel_launch(void* const* d_in, const int* in_sizes, int n_in,
                              void* d_out, int out_size, void* d_ws, size_t ws_size,
                              hipStream_t stream)
{
    const float* x      = (const float*)d_in[0];
    const float* ln1_g  = (const float*)d_in[1];
    const float* ln1_b  = (const float*)d_in[2];
    const float* qkv_w  = (const float*)d_in[3];
    const float* proj_w = (const float*)d_in[4];
    const float* proj_b = (const float*)d_in[5];
    const float* ln2_g  = (const float*)d_in[6];
    const float* ln2_b  = (const float*)d_in[7];
    const float* fc1_w  = (const float*)d_in[8];
    const float* fc1_b  = (const float*)d_in[9];
    const float* fc2_w  = (const float*)d_in[10];
    const float* fc2_b  = (const float*)d_in[11];
    float* out = (float*)d_out;

    char* ws = (char*)d_ws;
    bf16* QK = (bf16*)ws;                                   // T x 1536
    bf16* VT = (bf16*)(ws + (size_t)T_ * 1536 * 2);         // 48 x 64 x 2048
    bf16* G  = (bf16*)ws;                                   // T x 3072 (MLP phase)
    bf16* R1 = (bf16*)(ws + (size_t)T_ * HID_ * 2);         // T x 768

    // 1. LN1: x (f32) -> h (R1, bf16)
    ln_kernel<<<T_ / 4, 256, 0, stream>>>(x, ln1_g, ln1_b, R1);
    // 2. qkv = h @ qkv_w^T -> QK [T,1536] + VT (transposed V)
    gemm_bt<3><<<dim3(T_ / 128, 2304 / 128), 256, 0, stream>>>(
        R1, qkv_w, T_, 2304, C_, nullptr, nullptr, QK, VT);
    // 3. attention -> o (R1) [T,768] bf16
    attn_kernel<<<48 * 32, 256, 0, stream>>>(QK, VT, R1);
    // 4. x1 = x + o @ proj_w^T + proj_b -> d_out (f32)
    gemm_bt<1><<<dim3(T_ / 128, C_ / 128), 256, 0, stream>>>(
        R1, proj_w, T_, C_, C_, proj_b, x, out, nullptr);
    // 5. LN2: x1 (f32) -> h2 (R1, bf16)
    ln_kernel<<<T_ / 4, 256, 0, stream>>>(out, ln2_g, ln2_b, R1);
    // 6. g1 = gelu(h2 @ fc1_w^T + fc1_b) -> G [T,3072] bf16
    gemm_bt<2><<<dim3(T_ / 128, HID_ / 128), 256, 0, stream>>>(
        R1, fc1_w, T_, HID_, C_, fc1_b, nullptr, G, nullptr);
    // 7. out = x1 + g1 @ fc2_w^T + fc2_b -> d_out (in-place residual read, f32)
    gemm_bt<1><<<dim3(T_ / 128, C_ / 128), 256, 0, stream>>>(
        G, fc2_w, T_, C_, HID_, fc2_b, out, out, nullptr);
}

// Round 5
// 555.219 us; speedup vs baseline: 1.3123x; 1.1814x over previous
//
#include <hip/hip_runtime.h>
#include <math.h>

typedef __bf16 bf16;
typedef __bf16 bf16x4 __attribute__((ext_vector_type(4)));
typedef __bf16 bf16x8 __attribute__((ext_vector_type(8)));
typedef float  f32x4  __attribute__((ext_vector_type(4)));

#define B_   4
#define N_   2048
#define C_   768
#define H_   12
#define T_   8192      // B_*N_
#define HID_ 3072

// async global->LDS, 16 B per lane. LDS dest must be wave-uniform base + lane*16.
typedef const __attribute__((address_space(1))) unsigned int* as1_u32;
typedef __attribute__((address_space(3))) unsigned int* as3_u32;
__device__ __forceinline__ void gl_lds16(const void* g, void* l) {
    __builtin_amdgcn_global_load_lds((as1_u32)g, (as3_u32)l, 16, 0, 0);
}

// ---------------------------------------------------------------------------
// LayerNorm: one wave per row (C=768 = 12*64). f32 in, fp32 stats, bf16 out.
// ---------------------------------------------------------------------------
__global__ __launch_bounds__(256)
void ln_kernel(const float* __restrict__ inp, const float* __restrict__ g,
               const float* __restrict__ bsh, bf16* __restrict__ out)
{
    int wave = threadIdx.x >> 6, lane = threadIdx.x & 63;
    long long row = (long long)blockIdx.x * 4 + wave;
    const float* p = inp + row * C_;
    float v[12];
    #pragma unroll
    for (int i = 0; i < 12; i++) v[i] = p[i * 64 + lane];
    float s = 0.f, s2 = 0.f;
    #pragma unroll
    for (int i = 0; i < 12; i++) { s += v[i]; s2 += v[i] * v[i]; }
    #pragma unroll
    for (int m = 1; m < 64; m <<= 1) {
        s  += __shfl_xor(s,  m, 64);
        s2 += __shfl_xor(s2, m, 64);
    }
    float mu  = s  * (1.f / C_);
    float var = s2 * (1.f / C_) - mu * mu;
    float rs  = rsqrtf(var + 1e-5f);
    bf16* o = out + row * C_;
    #pragma unroll
    for (int i = 0; i < 12; i++) {
        int c = i * 64 + lane;
        o[c] = (bf16)(((v[i] - mu) * rs) * g[c] + bsh[c]);
    }
}

// ---------------------------------------------------------------------------
// GEMM: C[M,N] = A[M,K](bf16) @ Bw[N,K](f32)^T (+epilogue). 128x128, BK=32.
// (unchanged from round 4 — attention is this round's focus)
// ---------------------------------------------------------------------------
template<int MODE>
__global__ __launch_bounds__(256)
void gemm_bt(const bf16* __restrict__ A, const float* __restrict__ Bw,
             int M, int N, int K,
             const float* __restrict__ bias,
             const float* resid_f,
             void* out, bf16* out2)
{
    __shared__ bf16 At[128 * 32];
    __shared__ bf16 Bt[128 * 32];
    int tid  = threadIdx.x;
    int lane = tid & 63, wave = tid >> 6;
    int quad = lane >> 4, l15 = lane & 15;
    int bm = blockIdx.x, bn = blockIdx.y;
    int wm = wave >> 1, wn = wave & 1;

    f32x4 acc[4][4];
    f32x4 zero = {0.f, 0.f, 0.f, 0.f};
    #pragma unroll
    for (int mt = 0; mt < 4; mt++)
        #pragma unroll
        for (int nt = 0; nt < 4; nt++) acc[mt][nt] = zero;

    int arow = tid >> 2;          // 0..63
    int akof = (tid & 3) << 3;    // 0,8,16,24  (elements)
    const bf16*  ag = A  + (size_t)(bm * 128 + arow) * K + akof;
    const float* bg = Bw + (size_t)(bn * 128 + arow) * K + akof;

    for (int k0 = 0; k0 < K; k0 += 32) {
        gl_lds16(ag,                    &At[tid * 8]);
        gl_lds16(ag + (size_t)64 * K,   &At[2048 + tid * 8]);
        f32x4 b0a = *(const f32x4*)(bg);
        f32x4 b0b = *(const f32x4*)(bg + 4);
        f32x4 b1a = *(const f32x4*)(bg + (size_t)64 * K);
        f32x4 b1b = *(const f32x4*)(bg + (size_t)64 * K + 4);
        bf16x8 b0, b1;
        #pragma unroll
        for (int j = 0; j < 4; j++) {
            b0[j] = (bf16)b0a[j]; b0[4 + j] = (bf16)b0b[j];
            b1[j] = (bf16)b1a[j]; b1[4 + j] = (bf16)b1b[j];
        }
        *(bf16x8*)(&Bt[tid * 8])        = b0;
        *(bf16x8*)(&Bt[2048 + tid * 8]) = b1;
        ag += 32; bg += 32;
        __syncthreads();

        bf16x8 af[4], bfr[4];
        #pragma unroll
        for (int mt = 0; mt < 4; mt++)
            af[mt] = *(const bf16x8*)(&At[(wm * 64 + mt * 16 + l15) * 32 + quad * 8]);
        #pragma unroll
        for (int nt = 0; nt < 4; nt++)
            bfr[nt] = *(const bf16x8*)(&Bt[(wn * 64 + nt * 16 + l15) * 32 + quad * 8]);
        #pragma unroll
        for (int mt = 0; mt < 4; mt++)
            #pragma unroll
            for (int nt = 0; nt < 4; nt++)
                acc[mt][nt] = __builtin_amdgcn_mfma_f32_16x16x32_bf16(
                    af[mt], bfr[nt], acc[mt][nt], 0, 0, 0);
        __syncthreads();
    }

    if (MODE == 3) {
        if (bn < 12) {
            #pragma unroll
            for (int nt = 0; nt < 4; nt++) {
                int col = bn * 128 + wn * 64 + nt * 16 + l15;
                #pragma unroll
                for (int mt = 0; mt < 4; mt++)
                    #pragma unroll
                    for (int r = 0; r < 4; r++) {
                        int row = bm * 128 + wm * 64 + mt * 16 + quad * 4 + r;
                        ((bf16*)out)[(size_t)row * 1536 + col] = (bf16)acc[mt][nt][r];
                    }
            }
        } else {
            int b = bm >> 4;
            #pragma unroll
            for (int nt = 0; nt < 4; nt++) {
                int vcol = bn * 128 - 1536 + wn * 64 + nt * 16 + l15;  // 0..767
                int h = vcol >> 6, d = vcol & 63;
                size_t rowbase = ((size_t)(b * H_ + h) * 64 + d) * N_;
                #pragma unroll
                for (int mt = 0; mt < 4; mt++) {
                    int n0 = (bm & 15) * 128 + wm * 64 + mt * 16 + quad * 4;
                    bf16x4 pv;
                    #pragma unroll
                    for (int r = 0; r < 4; r++) pv[r] = (bf16)acc[mt][nt][r];
                    *(bf16x4*)(&out2[rowbase + n0]) = pv;
                }
            }
        }
    } else {
        #pragma unroll
        for (int nt = 0; nt < 4; nt++) {
            int col = bn * 128 + wn * 64 + nt * 16 + l15;
            float bv = bias[col];
            #pragma unroll
            for (int mt = 0; mt < 4; mt++) {
                #pragma unroll
                for (int r = 0; r < 4; r++) {
                    int row = bm * 128 + wm * 64 + mt * 16 + quad * 4 + r;
                    size_t idx = (size_t)row * N + col;
                    float v = acc[mt][nt][r] + bv;
                    if (MODE == 1) {
                        ((float*)out)[idx] = v + resid_f[idx];
                    } else {
                        float ge = 0.5f * v * (1.f + erff(v * 0.70710678118f));
                        ((bf16*)out)[idx] = (bf16)ge;
                    }
                }
            }
        }
    }
}

// ---------------------------------------------------------------------------
// Flash attention, transposed formulation.
//   S^T = K·Q^T  (C-layout: row=key, col=query -> per-lane softmax stats)
//   O^T = V^T·P^T (C-layout: row=d, col=query)
// All LDS tiles XOR-swizzled (16B chunk c -> c ^ (row&7)) => conflict-free
// b128 fragment reads. K/V double-buffered, staged via VGPRs, ONE barrier/iter.
// Block = (b,h,128 queries); 4 waves x 32 queries (2 q-tiles sharing K/V frags).
// ---------------------------------------------------------------------------
__global__ __launch_bounds__(256)
void attn_kernel(const bf16* __restrict__ qk, const bf16* __restrict__ vt,
                 bf16* __restrict__ o)
{
    __shared__ bf16 Kt[2][64 * 64];     // [key][d], swizzled
    __shared__ bf16 Vt[2][64 * 64];     // [d][key], swizzled
    __shared__ bf16 Pt[4][2][16 * 64];  // per-wave, per-qtile [query][key], swizzled

    int tid = threadIdx.x, lane = tid & 63, wave = tid >> 6;
    int quad = lane >> 4, l15 = lane & 15;
    int swz = (l15 & 7);                // read-side swizzle key
    int blk = blockIdx.x;
    int qb = blk & 15;      // 16 query blocks of 128
    int bh = blk >> 4;      // 0..47
    int b = bh / H_, h = bh % H_;

    const bf16* qbase = qk + (size_t)(b * N_) * 1536 + h * 64;
    const bf16* kbase = qbase + 768;
    const bf16* vtb   = vt + (size_t)(bh * 64) * N_;

    // Q fragments (B-operand layout: lane n=l15=query, k=quad*8+j=d)
    bf16x8 qf[2][2];
    #pragma unroll
    for (int qi = 0; qi < 2; qi++) {
        int q = qb * 128 + wave * 32 + qi * 16 + l15;
        const bf16* qp = qbase + (size_t)q * 1536 + quad * 8;
        qf[qi][0] = *(const bf16x8*)(qp);
        qf[qi][1] = *(const bf16x8*)(qp + 32);
    }

    // staging: thread t -> row t>>3 (and +32), 16B chunk t&7, swizzled store
    int srow = tid >> 3, schk = tid & 7;
    int soA = srow * 64 + ((schk ^ (srow & 7)) << 3);
    int soB = (srow + 32) * 64 + ((schk ^ (srow & 7)) << 3);

    bf16x8 kr0, kr1, vr0, vr1;
    const bf16* kg0 = kbase + (size_t)srow * 1536 + schk * 8;
    const bf16* vg0 = vtb + (size_t)srow * N_ + schk * 8;

    // load tile 0
    {
        kr0 = *(const bf16x8*)(kg0);
        kr1 = *(const bf16x8*)(kg0 + (size_t)32 * 1536);
        vr0 = *(const bf16x8*)(vg0);
        vr1 = *(const bf16x8*)(vg0 + (size_t)32 * N_);
        *(bf16x8*)(&Kt[0][soA]) = kr0;  *(bf16x8*)(&Kt[0][soB]) = kr1;
        *(bf16x8*)(&Vt[0][soA]) = vr0;  *(bf16x8*)(&Vt[0][soB]) = vr1;
    }
    __syncthreads();

    f32x4 oacc[2][4];
    f32x4 zero = {0.f, 0.f, 0.f, 0.f};
    #pragma unroll
    for (int qi = 0; qi < 2; qi++)
        #pragma unroll
        for (int nt = 0; nt < 4; nt++) oacc[qi][nt] = zero;
    float mrun[2] = {-1e30f, -1e30f}, lrun[2] = {0.f, 0.f};

    for (int kt = 0; kt < 32; kt++) {
        int cur = kt & 1;
        if (kt < 31) {   // prefetch next tile into regs (overlaps compute)
            const bf16* kg = kg0 + (size_t)(kt + 1) * 64 * 1536;
            const bf16* vg = vg0 + (size_t)(kt + 1) * 64;
            kr0 = *(const bf16x8*)(kg);
            kr1 = *(const bf16x8*)(kg + (size_t)32 * 1536);
            vr0 = *(const bf16x8*)(vg);
            vr1 = *(const bf16x8*)(vg + (size_t)32 * N_);
        }
        const bf16* KtC = &Kt[cur][0];
        const bf16* VtC = &Vt[cur][0];

        // ---- per q-tile: S^T = K Q^T, softmax, P write ----
        #pragma unroll
        for (int qi = 0; qi < 2; qi++) {
            f32x4 s[4];
            #pragma unroll
            for (int nt = 0; nt < 4; nt++) {
                const bf16* krow = KtC + (nt * 16 + l15) * 64;
                bf16x8 ka0 = *(const bf16x8*)(krow + ((quad ^ swz) << 3));
                bf16x8 ka1 = *(const bf16x8*)(krow + (((4 + quad) ^ swz) << 3));
                f32x4 sv = zero;
                sv = __builtin_amdgcn_mfma_f32_16x16x32_bf16(ka0, qf[qi][0], sv, 0, 0, 0);
                sv = __builtin_amdgcn_mfma_f32_16x16x32_bf16(ka1, qf[qi][1], sv, 0, 0, 0);
                s[nt] = sv;
            }
            // per-lane softmax (query = col = l15; reduce across quads)
            float mx = -1e30f;
            #pragma unroll
            for (int nt = 0; nt < 4; nt++)
                #pragma unroll
                for (int r = 0; r < 4; r++) mx = fmaxf(mx, s[nt][r]);
            mx = fmaxf(mx, __shfl_xor(mx, 16, 64));
            mx = fmaxf(mx, __shfl_xor(mx, 32, 64));
            float mnew = fmaxf(mrun[qi], mx * 0.125f);
            float al   = __expf(mrun[qi] - mnew);
            mrun[qi] = mnew;
            float ps = 0.f;
            #pragma unroll
            for (int nt = 0; nt < 4; nt++)
                #pragma unroll
                for (int r = 0; r < 4; r++) {
                    float pv = __expf(s[nt][r] * 0.125f - mnew);
                    s[nt][r] = pv;
                    ps += pv;
                }
            ps += __shfl_xor(ps, 16, 64);
            ps += __shfl_xor(ps, 32, 64);
            lrun[qi] = lrun[qi] * al + ps;
            #pragma unroll
            for (int nt = 0; nt < 4; nt++) oacc[qi][nt] *= al;
            // P[query=l15][key nt*16+quad*4+r] -> swizzled b64 stores
            bf16* pw = &Pt[wave][qi][0];
            #pragma unroll
            for (int nt = 0; nt < 4; nt++) {
                bf16x4 pk;
                #pragma unroll
                for (int r = 0; r < 4; r++) pk[r] = (bf16)s[nt][r];
                int ofs = l15 * 64 + (((nt * 2 + (quad >> 1)) ^ swz) << 3) + ((quad & 1) << 2);
                *(bf16x4*)(&pw[ofs]) = pk;
            }
        }

        // ---- O^T += V^T P^T ----
        #pragma unroll
        for (int kc = 0; kc < 2; kc++) {
            int pofs = l15 * 64 + (((kc * 4 + quad) ^ swz) << 3);
            bf16x8 pb0 = *(const bf16x8*)(&Pt[wave][0][pofs]);
            bf16x8 pb1 = *(const bf16x8*)(&Pt[wave][1][pofs]);
            #pragma unroll
            for (int nt = 0; nt < 4; nt++) {
                bf16x8 va = *(const bf16x8*)(VtC + (nt * 16 + l15) * 64 +
                                             (((kc * 4 + quad) ^ swz) << 3));
                oacc[0][nt] = __builtin_amdgcn_mfma_f32_16x16x32_bf16(va, pb0, oacc[0][nt], 0, 0, 0);
                oacc[1][nt] = __builtin_amdgcn_mfma_f32_16x16x32_bf16(va, pb1, oacc[1][nt], 0, 0, 0);
            }
        }

        if (kt < 31) {   // stage prefetched tile into the other buffer
            int nxt = cur ^ 1;
            *(bf16x8*)(&Kt[nxt][soA]) = kr0;  *(bf16x8*)(&Kt[nxt][soB]) = kr1;
            *(bf16x8*)(&Vt[nxt][soA]) = vr0;  *(bf16x8*)(&Vt[nxt][soB]) = vr1;
        }
        __syncthreads();
    }

    // write O: O^T C-layout => lane l15 = query, rows = d -> b64 stores
    #pragma unroll
    for (int qi = 0; qi < 2; qi++) {
        int q = qb * 128 + wave * 32 + qi * 16 + l15;
        float inv = 1.f / lrun[qi];
        bf16* ob = o + (size_t)(b * N_ + q) * C_ + h * 64 + quad * 4;
        #pragma unroll
        for (int nt = 0; nt < 4; nt++) {
            bf16x4 pk;
            #pragma unroll
            for (int r = 0; r < 4; r++) pk[r] = (bf16)(oacc[qi][nt][r] * inv);
            *(bf16x4*)(&ob[nt * 16]) = pk;
        }
    }
}

// ---------------------------------------------------------------------------
// Workspace (62.9 MB):
//   [0, 25165824)          QK [T,1536] bf16      (attention phase)
//   [25165824, 37748736)   V_T [48][64][2048] bf16
//   [0, 50331648)          gelu(fc1) [T,3072] bf16 (MLP phase, reuses above)
//   [50331648, 62914560)   R1: h / o / h2 [T,768] bf16
// Residual stream x1 lives f32 in d_out.
// ---------------------------------------------------------------------------
extern "C" void kernel_launch(void* const* d_in, const int* in_sizes, int n_in,
                              void* d_out, int out_size, void* d_ws, size_t ws_size,
                              hipStream_t stream)
{
    const float* x      = (const float*)d_in[0];
    const float* ln1_g  = (const float*)d_in[1];
    const float* ln1_b  = (const float*)d_in[2];
    const float* qkv_w  = (const float*)d_in[3];
    const float* proj_w = (const float*)d_in[4];
    const float* proj_b = (const float*)d_in[5];
    const float* ln2_g  = (const float*)d_in[6];
    const float* ln2_b  = (const float*)d_in[7];
    const float* fc1_w  = (const float*)d_in[8];
    const float* fc1_b  = (const float*)d_in[9];
    const float* fc2_w  = (const float*)d_in[10];
    const float* fc2_b  = (const float*)d_in[11];
    float* out = (float*)d_out;

    char* ws = (char*)d_ws;
    bf16* QK = (bf16*)ws;                                   // T x 1536
    bf16* VT = (bf16*)(ws + (size_t)T_ * 1536 * 2);         // 48 x 64 x 2048
    bf16* G  = (bf16*)ws;                                   // T x 3072 (MLP phase)
    bf16* R1 = (bf16*)(ws + (size_t)T_ * HID_ * 2);         // T x 768

    // 1. LN1: x (f32) -> h (R1, bf16)
    ln_kernel<<<T_ / 4, 256, 0, stream>>>(x, ln1_g, ln1_b, R1);
    // 2. qkv = h @ qkv_w^T -> QK [T,1536] + VT (transposed V)
    gemm_bt<3><<<dim3(T_ / 128, 2304 / 128), 256, 0, stream>>>(
        R1, qkv_w, T_, 2304, C_, nullptr, nullptr, QK, VT);
    // 3. attention -> o (R1) [T,768] bf16
    attn_kernel<<<48 * 16, 256, 0, stream>>>(QK, VT, R1);
    // 4. x1 = x + o @ proj_w^T + proj_b -> d_out (f32)
    gemm_bt<1><<<dim3(T_ / 128, C_ / 128), 256, 0, stream>>>(
        R1, proj_w, T_, C_, C_, proj_b, x, out, nullptr);
    // 5. LN2: x1 (f32) -> h2 (R1, bf16)
    ln_kernel<<<T_ / 4, 256, 0, stream>>>(out, ln2_g, ln2_b, R1);
    // 6. g1 = gelu(h2 @ fc1_w^T + fc1_b) -> G [T,3072] bf16
    gemm_bt<2><<<dim3(T_ / 128, HID_ / 128), 256, 0, stream>>>(
        R1, fc1_w, T_, HID_, C_, fc1_b, nullptr, G, nullptr);
    // 7. out = x1 + g1 @ fc2_w^T + fc2_b -> d_out (in-place residual read, f32)
    gemm_bt<1><<<dim3(T_ / 128, C_ / 128), 256, 0, stream>>>(
        G, fc2_w, T_, C_, HID_, fc2_b, out, out, nullptr);
}

// Round 6
// 527.046 us; speedup vs baseline: 1.3825x; 1.0535x over previous
//
#include <hip/hip_runtime.h>
#include <math.h>

typedef __bf16 bf16;
typedef __bf16 bf16x4 __attribute__((ext_vector_type(4)));
typedef __bf16 bf16x8 __attribute__((ext_vector_type(8)));
typedef float  f32x4  __attribute__((ext_vector_type(4)));

#define B_   4
#define N_   2048
#define C_   768
#define H_   12
#define T_   8192      // B_*N_
#define HID_ 3072

// async global->LDS, 16 B per lane. LDS dest must be wave-uniform base + lane*16.
typedef const __attribute__((address_space(1))) unsigned int* as1_u32;
typedef __attribute__((address_space(3))) unsigned int* as3_u32;
__device__ __forceinline__ void gl_lds16(const void* g, void* l) {
    __builtin_amdgcn_global_load_lds((as1_u32)g, (as3_u32)l, 16, 0, 0);
}

// ---------------------------------------------------------------------------
// LayerNorm: one wave per row (C=768 = 12*64). f32 in, fp32 stats, bf16 out.
// ---------------------------------------------------------------------------
__global__ __launch_bounds__(256)
void ln_kernel(const float* __restrict__ inp, const float* __restrict__ g,
               const float* __restrict__ bsh, bf16* __restrict__ out)
{
    int wave = threadIdx.x >> 6, lane = threadIdx.x & 63;
    long long row = (long long)blockIdx.x * 4 + wave;
    const float* p = inp + row * C_;
    float v[12];
    #pragma unroll
    for (int i = 0; i < 12; i++) v[i] = p[i * 64 + lane];
    float s = 0.f, s2 = 0.f;
    #pragma unroll
    for (int i = 0; i < 12; i++) { s += v[i]; s2 += v[i] * v[i]; }
    #pragma unroll
    for (int m = 1; m < 64; m <<= 1) {
        s  += __shfl_xor(s,  m, 64);
        s2 += __shfl_xor(s2, m, 64);
    }
    float mu  = s  * (1.f / C_);
    float var = s2 * (1.f / C_) - mu * mu;
    float rs  = rsqrtf(var + 1e-5f);
    bf16* o = out + row * C_;
    #pragma unroll
    for (int i = 0; i < 12; i++) {
        int c = i * 64 + lane;
        o[c] = (bf16)(((v[i] - mu) * rs) * g[c] + bsh[c]);
    }
}

// ---------------------------------------------------------------------------
// GEMM (wide-N): C = A(bf16) @ Bw(f32)^T. 128x128 tile, BK=32.
// LDS chunk permutation c = row*4 + (q ^ ((row>>1)&3)) -> conflict-free b128
// fragment reads while keeping global_load_lds's lane-contiguous dest.
// MODE 2: out bf16 = gelu(acc + bias)   (fc1)
// MODE 3: qkv split: cols [0,1536) -> QK bf16; cols [1536,2304) -> V^T
// ---------------------------------------------------------------------------
template<int MODE>
__global__ __launch_bounds__(256)
void gemm_bt(const bf16* __restrict__ A, const float* __restrict__ Bw,
             int M, int N, int K,
             const float* __restrict__ bias,
             void* out, bf16* out2)
{
    __shared__ bf16 At[128 * 32];
    __shared__ bf16 Bt[128 * 32];
    int tid  = threadIdx.x;
    int lane = tid & 63, wave = tid >> 6;
    int quad = lane >> 4, l15 = lane & 15;
    int bm = blockIdx.x, bn = blockIdx.y;
    int wm = wave >> 1, wn = wave & 1;
    int swz = (l15 >> 1) & 3;

    f32x4 acc[4][4];
    f32x4 zero = {0.f, 0.f, 0.f, 0.f};
    #pragma unroll
    for (int mt = 0; mt < 4; mt++)
        #pragma unroll
        for (int nt = 0; nt < 4; nt++) acc[mt][nt] = zero;

    int arow = tid >> 2;                              // 0..63
    int aq   = (tid & 3) ^ ((arow >> 1) & 3);         // permuted k-chunk
    const bf16*  ag = A  + (size_t)(bm * 128 + arow) * K + aq * 8;
    const float* bg = Bw + (size_t)(bn * 128 + arow) * K + aq * 8;

    for (int k0 = 0; k0 < K; k0 += 32) {
        gl_lds16(ag,                    &At[tid * 8]);
        gl_lds16(ag + (size_t)64 * K,   &At[2048 + tid * 8]);
        f32x4 b0a = *(const f32x4*)(bg);
        f32x4 b0b = *(const f32x4*)(bg + 4);
        f32x4 b1a = *(const f32x4*)(bg + (size_t)64 * K);
        f32x4 b1b = *(const f32x4*)(bg + (size_t)64 * K + 4);
        bf16x8 b0, b1;
        #pragma unroll
        for (int j = 0; j < 4; j++) {
            b0[j] = (bf16)b0a[j]; b0[4 + j] = (bf16)b0b[j];
            b1[j] = (bf16)b1a[j]; b1[4 + j] = (bf16)b1b[j];
        }
        *(bf16x8*)(&Bt[tid * 8])        = b0;
        *(bf16x8*)(&Bt[2048 + tid * 8]) = b1;
        ag += 32; bg += 32;
        __syncthreads();

        bf16x8 af[4], bfr[4];
        #pragma unroll
        for (int mt = 0; mt < 4; mt++)
            af[mt] = *(const bf16x8*)(&At[wm * 2048 + (mt * 16 + l15) * 32 + ((quad ^ swz) << 3)]);
        #pragma unroll
        for (int nt = 0; nt < 4; nt++)
            bfr[nt] = *(const bf16x8*)(&Bt[wn * 2048 + (nt * 16 + l15) * 32 + ((quad ^ swz) << 3)]);
        #pragma unroll
        for (int mt = 0; mt < 4; mt++)
            #pragma unroll
            for (int nt = 0; nt < 4; nt++)
                acc[mt][nt] = __builtin_amdgcn_mfma_f32_16x16x32_bf16(
                    af[mt], bfr[nt], acc[mt][nt], 0, 0, 0);
        __syncthreads();
    }

    if (MODE == 3) {
        if (bn < 12) {
            #pragma unroll
            for (int nt = 0; nt < 4; nt++) {
                int col = bn * 128 + wn * 64 + nt * 16 + l15;
                #pragma unroll
                for (int mt = 0; mt < 4; mt++)
                    #pragma unroll
                    for (int r = 0; r < 4; r++) {
                        int row = bm * 128 + wm * 64 + mt * 16 + quad * 4 + r;
                        ((bf16*)out)[(size_t)row * 1536 + col] = (bf16)acc[mt][nt][r];
                    }
            }
        } else {
            int b = bm >> 4;
            #pragma unroll
            for (int nt = 0; nt < 4; nt++) {
                int vcol = bn * 128 - 1536 + wn * 64 + nt * 16 + l15;  // 0..767
                int h = vcol >> 6, d = vcol & 63;
                size_t rowbase = ((size_t)(b * H_ + h) * 64 + d) * N_;
                #pragma unroll
                for (int mt = 0; mt < 4; mt++) {
                    int n0 = (bm & 15) * 128 + wm * 64 + mt * 16 + quad * 4;
                    bf16x4 pv;
                    #pragma unroll
                    for (int r = 0; r < 4; r++) pv[r] = (bf16)acc[mt][nt][r];
                    *(bf16x4*)(&out2[rowbase + n0]) = pv;
                }
            }
        }
    } else {
        #pragma unroll
        for (int nt = 0; nt < 4; nt++) {
            int col = bn * 128 + wn * 64 + nt * 16 + l15;
            float bv = bias[col];
            #pragma unroll
            for (int mt = 0; mt < 4; mt++) {
                #pragma unroll
                for (int r = 0; r < 4; r++) {
                    int row = bm * 128 + wm * 64 + mt * 16 + quad * 4 + r;
                    size_t idx = (size_t)row * N + col;
                    float v = acc[mt][nt][r] + bv;
                    float ge = 0.5f * v * (1.f + erff(v * 0.70710678118f));
                    ((bf16*)out)[idx] = (bf16)ge;
                }
            }
        }
    }
}

// ---------------------------------------------------------------------------
// GEMM (narrow-N, N=768): 128x64 tile, BK=32, DOUBLE-buffered LDS with one
// barrier/iter + prefetch (for proj/fc2 where grid would otherwise be 1.5
// blocks/CU). out f32 = acc + bias + resid (resid may alias out).
// ---------------------------------------------------------------------------
__global__ __launch_bounds__(256)
void gemm64(const bf16* __restrict__ A, const float* __restrict__ Bw,
            int K, const float* __restrict__ bias,
            const float* resid_f, float* out)
{
    __shared__ bf16 At[2][128 * 32];
    __shared__ bf16 Bt[2][64 * 32];
    int tid  = threadIdx.x;
    int lane = tid & 63, wave = tid >> 6;
    int quad = lane >> 4, l15 = lane & 15;
    int bm = blockIdx.x, bn = blockIdx.y;
    int wm = wave >> 1, wn = wave & 1;    // wave: rows wm*64+, cols wn*32+
    int swz = (l15 >> 1) & 3;

    f32x4 acc[4][2];
    f32x4 zero = {0.f, 0.f, 0.f, 0.f};
    #pragma unroll
    for (int mt = 0; mt < 4; mt++)
        #pragma unroll
        for (int nt = 0; nt < 2; nt++) acc[mt][nt] = zero;

    int arow = tid >> 2;                              // 0..63
    int aq   = (tid & 3) ^ ((arow >> 1) & 3);         // permuted k-chunk
    const bf16*  ag = A  + (size_t)(bm * 128 + arow) * K + aq * 8;
    const float* bg = Bw + (size_t)(bn * 64  + arow) * K + aq * 8;

    // stage tile 0 into buffer 0
    {
        gl_lds16(ag,                  &At[0][tid * 8]);
        gl_lds16(ag + (size_t)64 * K, &At[0][2048 + tid * 8]);
        f32x4 ba = *(const f32x4*)(bg);
        f32x4 bb = *(const f32x4*)(bg + 4);
        bf16x8 b0;
        #pragma unroll
        for (int j = 0; j < 4; j++) { b0[j] = (bf16)ba[j]; b0[4 + j] = (bf16)bb[j]; }
        *(bf16x8*)(&Bt[0][tid * 8]) = b0;
    }
    __syncthreads();

    int nk = K >> 5;
    for (int kt = 0; kt < nk; kt++) {
        int cur = kt & 1, nxt = cur ^ 1;
        if (kt + 1 < nk) {
            const bf16*  agn = ag + (size_t)(kt + 1) * 32;
            const float* bgn = bg + (size_t)(kt + 1) * 32;
            gl_lds16(agn,                  &At[nxt][tid * 8]);
            gl_lds16(agn + (size_t)64 * K, &At[nxt][2048 + tid * 8]);
            f32x4 ba = *(const f32x4*)(bgn);
            f32x4 bb = *(const f32x4*)(bgn + 4);
            bf16x8 b0;
            #pragma unroll
            for (int j = 0; j < 4; j++) { b0[j] = (bf16)ba[j]; b0[4 + j] = (bf16)bb[j]; }
            *(bf16x8*)(&Bt[nxt][tid * 8]) = b0;
        }
        bf16x8 af[4], bfr[2];
        #pragma unroll
        for (int mt = 0; mt < 4; mt++)
            af[mt] = *(const bf16x8*)(&At[cur][wm * 2048 + (mt * 16 + l15) * 32 + ((quad ^ swz) << 3)]);
        #pragma unroll
        for (int nt = 0; nt < 2; nt++)
            bfr[nt] = *(const bf16x8*)(&Bt[cur][(wn * 32 + nt * 16 + l15) * 32 + ((quad ^ swz) << 3)]);
        #pragma unroll
        for (int mt = 0; mt < 4; mt++)
            #pragma unroll
            for (int nt = 0; nt < 2; nt++)
                acc[mt][nt] = __builtin_amdgcn_mfma_f32_16x16x32_bf16(
                    af[mt], bfr[nt], acc[mt][nt], 0, 0, 0);
        __syncthreads();
    }

    #pragma unroll
    for (int nt = 0; nt < 2; nt++) {
        int col = bn * 64 + wn * 32 + nt * 16 + l15;
        float bv = bias[col];
        #pragma unroll
        for (int mt = 0; mt < 4; mt++) {
            #pragma unroll
            for (int r = 0; r < 4; r++) {
                int row = bm * 128 + wm * 64 + mt * 16 + quad * 4 + r;
                size_t idx = (size_t)row * C_ + col;
                out[idx] = acc[mt][nt][r] + bv + resid_f[idx];
            }
        }
    }
}

// ---------------------------------------------------------------------------
// Flash attention, transposed formulation (unchanged from round 5).
// ---------------------------------------------------------------------------
__global__ __launch_bounds__(256)
void attn_kernel(const bf16* __restrict__ qk, const bf16* __restrict__ vt,
                 bf16* __restrict__ o)
{
    __shared__ bf16 Kt[2][64 * 64];     // [key][d], swizzled
    __shared__ bf16 Vt[2][64 * 64];     // [d][key], swizzled
    __shared__ bf16 Pt[4][2][16 * 64];  // per-wave, per-qtile [query][key], swizzled

    int tid = threadIdx.x, lane = tid & 63, wave = tid >> 6;
    int quad = lane >> 4, l15 = lane & 15;
    int swz = (l15 & 7);                // read-side swizzle key
    int blk = blockIdx.x;
    int qb = blk & 15;      // 16 query blocks of 128
    int bh = blk >> 4;      // 0..47
    int b = bh / H_, h = bh % H_;

    const bf16* qbase = qk + (size_t)(b * N_) * 1536 + h * 64;
    const bf16* kbase = qbase + 768;
    const bf16* vtb   = vt + (size_t)(bh * 64) * N_;

    bf16x8 qf[2][2];
    #pragma unroll
    for (int qi = 0; qi < 2; qi++) {
        int q = qb * 128 + wave * 32 + qi * 16 + l15;
        const bf16* qp = qbase + (size_t)q * 1536 + quad * 8;
        qf[qi][0] = *(const bf16x8*)(qp);
        qf[qi][1] = *(const bf16x8*)(qp + 32);
    }

    int srow = tid >> 3, schk = tid & 7;
    int soA = srow * 64 + ((schk ^ (srow & 7)) << 3);
    int soB = (srow + 32) * 64 + ((schk ^ (srow & 7)) << 3);

    bf16x8 kr0, kr1, vr0, vr1;
    const bf16* kg0 = kbase + (size_t)srow * 1536 + schk * 8;
    const bf16* vg0 = vtb + (size_t)srow * N_ + schk * 8;

    {
        kr0 = *(const bf16x8*)(kg0);
        kr1 = *(const bf16x8*)(kg0 + (size_t)32 * 1536);
        vr0 = *(const bf16x8*)(vg0);
        vr1 = *(const bf16x8*)(vg0 + (size_t)32 * N_);
        *(bf16x8*)(&Kt[0][soA]) = kr0;  *(bf16x8*)(&Kt[0][soB]) = kr1;
        *(bf16x8*)(&Vt[0][soA]) = vr0;  *(bf16x8*)(&Vt[0][soB]) = vr1;
    }
    __syncthreads();

    f32x4 oacc[2][4];
    f32x4 zero = {0.f, 0.f, 0.f, 0.f};
    #pragma unroll
    for (int qi = 0; qi < 2; qi++)
        #pragma unroll
        for (int nt = 0; nt < 4; nt++) oacc[qi][nt] = zero;
    float mrun[2] = {-1e30f, -1e30f}, lrun[2] = {0.f, 0.f};

    for (int kt = 0; kt < 32; kt++) {
        int cur = kt & 1;
        if (kt < 31) {
            const bf16* kg = kg0 + (size_t)(kt + 1) * 64 * 1536;
            const bf16* vg = vg0 + (size_t)(kt + 1) * 64;
            kr0 = *(const bf16x8*)(kg);
            kr1 = *(const bf16x8*)(kg + (size_t)32 * 1536);
            vr0 = *(const bf16x8*)(vg);
            vr1 = *(const bf16x8*)(vg + (size_t)32 * N_);
        }
        const bf16* KtC = &Kt[cur][0];
        const bf16* VtC = &Vt[cur][0];

        #pragma unroll
        for (int qi = 0; qi < 2; qi++) {
            f32x4 s[4];
            #pragma unroll
            for (int nt = 0; nt < 4; nt++) {
                const bf16* krow = KtC + (nt * 16 + l15) * 64;
                bf16x8 ka0 = *(const bf16x8*)(krow + ((quad ^ swz) << 3));
                bf16x8 ka1 = *(const bf16x8*)(krow + (((4 + quad) ^ swz) << 3));
                f32x4 sv = zero;
                sv = __builtin_amdgcn_mfma_f32_16x16x32_bf16(ka0, qf[qi][0], sv, 0, 0, 0);
                sv = __builtin_amdgcn_mfma_f32_16x16x32_bf16(ka1, qf[qi][1], sv, 0, 0, 0);
                s[nt] = sv;
            }
            float mx = -1e30f;
            #pragma unroll
            for (int nt = 0; nt < 4; nt++)
                #pragma unroll
                for (int r = 0; r < 4; r++) mx = fmaxf(mx, s[nt][r]);
            mx = fmaxf(mx, __shfl_xor(mx, 16, 64));
            mx = fmaxf(mx, __shfl_xor(mx, 32, 64));
            float mnew = fmaxf(mrun[qi], mx * 0.125f);
            float al   = __expf(mrun[qi] - mnew);
            mrun[qi] = mnew;
            float ps = 0.f;
            #pragma unroll
            for (int nt = 0; nt < 4; nt++)
                #pragma unroll
                for (int r = 0; r < 4; r++) {
                    float pv = __expf(s[nt][r] * 0.125f - mnew);
                    s[nt][r] = pv;
                    ps += pv;
                }
            ps += __shfl_xor(ps, 16, 64);
            ps += __shfl_xor(ps, 32, 64);
            lrun[qi] = lrun[qi] * al + ps;
            #pragma unroll
            for (int nt = 0; nt < 4; nt++) oacc[qi][nt] *= al;
            bf16* pw = &Pt[wave][qi][0];
            #pragma unroll
            for (int nt = 0; nt < 4; nt++) {
                bf16x4 pk;
                #pragma unroll
                for (int r = 0; r < 4; r++) pk[r] = (bf16)s[nt][r];
                int ofs = l15 * 64 + (((nt * 2 + (quad >> 1)) ^ swz) << 3) + ((quad & 1) << 2);
                *(bf16x4*)(&pw[ofs]) = pk;
            }
        }

        #pragma unroll
        for (int kc = 0; kc < 2; kc++) {
            int pofs = l15 * 64 + (((kc * 4 + quad) ^ swz) << 3);
            bf16x8 pb0 = *(const bf16x8*)(&Pt[wave][0][pofs]);
            bf16x8 pb1 = *(const bf16x8*)(&Pt[wave][1][pofs]);
            #pragma unroll
            for (int nt = 0; nt < 4; nt++) {
                bf16x8 va = *(const bf16x8*)(VtC + (nt * 16 + l15) * 64 +
                                             (((kc * 4 + quad) ^ swz) << 3));
                oacc[0][nt] = __builtin_amdgcn_mfma_f32_16x16x32_bf16(va, pb0, oacc[0][nt], 0, 0, 0);
                oacc[1][nt] = __builtin_amdgcn_mfma_f32_16x16x32_bf16(va, pb1, oacc[1][nt], 0, 0, 0);
            }
        }

        if (kt < 31) {
            int nxt = cur ^ 1;
            *(bf16x8*)(&Kt[nxt][soA]) = kr0;  *(bf16x8*)(&Kt[nxt][soB]) = kr1;
            *(bf16x8*)(&Vt[nxt][soA]) = vr0;  *(bf16x8*)(&Vt[nxt][soB]) = vr1;
        }
        __syncthreads();
    }

    #pragma unroll
    for (int qi = 0; qi < 2; qi++) {
        int q = qb * 128 + wave * 32 + qi * 16 + l15;
        float inv = 1.f / lrun[qi];
        bf16* ob = o + (size_t)(b * N_ + q) * C_ + h * 64 + quad * 4;
        #pragma unroll
        for (int nt = 0; nt < 4; nt++) {
            bf16x4 pk;
            #pragma unroll
            for (int r = 0; r < 4; r++) pk[r] = (bf16)(oacc[qi][nt][r] * inv);
            *(bf16x4*)(&ob[nt * 16]) = pk;
        }
    }
}

// ---------------------------------------------------------------------------
// Workspace (62.9 MB):
//   [0, 25165824)          QK [T,1536] bf16      (attention phase)
//   [25165824, 37748736)   V_T [48][64][2048] bf16
//   [0, 50331648)          gelu(fc1) [T,3072] bf16 (MLP phase, reuses above)
//   [50331648, 62914560)   R1: h / o / h2 [T,768] bf16
// Residual stream x1 lives f32 in d_out.
// ---------------------------------------------------------------------------
extern "C" void kernel_launch(void* const* d_in, const int* in_sizes, int n_in,
                              void* d_out, int out_size, void* d_ws, size_t ws_size,
                              hipStream_t stream)
{
    const float* x      = (const float*)d_in[0];
    const float* ln1_g  = (const float*)d_in[1];
    const float* ln1_b  = (const float*)d_in[2];
    const float* qkv_w  = (const float*)d_in[3];
    const float* proj_w = (const float*)d_in[4];
    const float* proj_b = (const float*)d_in[5];
    const float* ln2_g  = (const float*)d_in[6];
    const float* ln2_b  = (const float*)d_in[7];
    const float* fc1_w  = (const float*)d_in[8];
    const float* fc1_b  = (const float*)d_in[9];
    const float* fc2_w  = (const float*)d_in[10];
    const float* fc2_b  = (const float*)d_in[11];
    float* out = (float*)d_out;

    char* ws = (char*)d_ws;
    bf16* QK = (bf16*)ws;                                   // T x 1536
    bf16* VT = (bf16*)(ws + (size_t)T_ * 1536 * 2);         // 48 x 64 x 2048
    bf16* G  = (bf16*)ws;                                   // T x 3072 (MLP phase)
    bf16* R1 = (bf16*)(ws + (size_t)T_ * HID_ * 2);         // T x 768

    // 1. LN1: x (f32) -> h (R1, bf16)
    ln_kernel<<<T_ / 4, 256, 0, stream>>>(x, ln1_g, ln1_b, R1);
    // 2. qkv = h @ qkv_w^T -> QK [T,1536] + VT (transposed V)
    gemm_bt<3><<<dim3(T_ / 128, 2304 / 128), 256, 0, stream>>>(
        R1, qkv_w, T_, 2304, C_, nullptr, QK, VT);
    // 3. attention -> o (R1) [T,768] bf16
    attn_kernel<<<48 * 16, 256, 0, stream>>>(QK, VT, R1);
    // 4. x1 = x + o @ proj_w^T + proj_b -> d_out (f32)
    gemm64<<<dim3(T_ / 128, C_ / 64), 256, 0, stream>>>(
        R1, proj_w, C_, proj_b, x, out);
    // 5. LN2: x1 (f32) -> h2 (R1, bf16)
    ln_kernel<<<T_ / 4, 256, 0, stream>>>(out, ln2_g, ln2_b, R1);
    // 6. g1 = gelu(h2 @ fc1_w^T + fc1_b) -> G [T,3072] bf16
    gemm_bt<2><<<dim3(T_ / 128, HID_ / 128), 256, 0, stream>>>(
        R1, fc1_w, T_, HID_, C_, fc1_b, G, nullptr);
    // 7. out = x1 + g1 @ fc2_w^T + fc2_b -> d_out (in-place residual read, f32)
    gemm64<<<dim3(T_ / 128, C_ / 64), 256, 0, stream>>>(
        G, fc2_w, HID_, fc2_b, out, out);
}

// Round 7
// 495.625 us; speedup vs baseline: 1.4701x; 1.0634x over previous
//
#include <hip/hip_runtime.h>
#include <math.h>

typedef __bf16 bf16;
typedef __bf16 bf16x4 __attribute__((ext_vector_type(4)));
typedef __bf16 bf16x8 __attribute__((ext_vector_type(8)));
typedef float  f32x4  __attribute__((ext_vector_type(4)));

#define B_   4
#define N_   2048
#define C_   768
#define H_   12
#define T_   8192      // B_*N_
#define HID_ 3072

// async global->LDS, 16 B per lane. LDS dest must be wave-uniform base + lane*16.
typedef const __attribute__((address_space(1))) unsigned int* as1_u32;
typedef __attribute__((address_space(3))) unsigned int* as3_u32;
__device__ __forceinline__ void gl_lds16(const void* g, void* l) {
    __builtin_amdgcn_global_load_lds((as1_u32)g, (as3_u32)l, 16, 0, 0);
}

// ---------------------------------------------------------------------------
// LayerNorm: one wave per row (C=768 = 12*64). f32 in, fp32 stats, bf16 out.
// ---------------------------------------------------------------------------
__global__ __launch_bounds__(256)
void ln_kernel(const float* __restrict__ inp, const float* __restrict__ g,
               const float* __restrict__ bsh, bf16* __restrict__ out)
{
    int wave = threadIdx.x >> 6, lane = threadIdx.x & 63;
    long long row = (long long)blockIdx.x * 4 + wave;
    const float* p = inp + row * C_;
    float v[12];
    #pragma unroll
    for (int i = 0; i < 12; i++) v[i] = p[i * 64 + lane];
    float s = 0.f, s2 = 0.f;
    #pragma unroll
    for (int i = 0; i < 12; i++) { s += v[i]; s2 += v[i] * v[i]; }
    #pragma unroll
    for (int m = 1; m < 64; m <<= 1) {
        s  += __shfl_xor(s,  m, 64);
        s2 += __shfl_xor(s2, m, 64);
    }
    float mu  = s  * (1.f / C_);
    float var = s2 * (1.f / C_) - mu * mu;
    float rs  = rsqrtf(var + 1e-5f);
    bf16* o = out + row * C_;
    #pragma unroll
    for (int i = 0; i < 12; i++) {
        int c = i * 64 + lane;
        o[c] = (bf16)(((v[i] - mu) * rs) * g[c] + bsh[c]);
    }
}

// ---------------------------------------------------------------------------
// GEMM (wide-N): C = A(bf16) @ Bw(f32)^T. 128x128 tile, BK=32, DOUBLE-buffered
// LDS, one barrier/iter. Prefetch pipeline: A via async DMA (drains at the
// end-of-iter barrier, overlapped by compute); B into REGISTERS during
// compute, converted+staged to LDS only after compute (vmcnt wait lands
// post-compute, not pre-compute). Chunk permutation keeps b128 frag reads
// conflict-free with the DMA's lane-contiguous dest.
// MODE 2: out bf16 = gelu(acc + bias)   (fc1)
// MODE 3: qkv split: cols [0,1536) -> QK bf16; cols [1536,2304) -> V^T
// ---------------------------------------------------------------------------
template<int MODE>
__global__ __launch_bounds__(256)
void gemm_bt(const bf16* __restrict__ A, const float* __restrict__ Bw,
             int M, int N, int K,
             const float* __restrict__ bias,
             void* out, bf16* out2)
{
    __shared__ bf16 At[2][128 * 32];
    __shared__ bf16 Bt[2][128 * 32];
    int tid  = threadIdx.x;
    int lane = tid & 63, wave = tid >> 6;
    int quad = lane >> 4, l15 = lane & 15;
    int bm = blockIdx.x, bn = blockIdx.y;
    int wm = wave >> 1, wn = wave & 1;
    int swz = (l15 >> 1) & 3;

    f32x4 acc[4][4];
    f32x4 zero = {0.f, 0.f, 0.f, 0.f};
    #pragma unroll
    for (int mt = 0; mt < 4; mt++)
        #pragma unroll
        for (int nt = 0; nt < 4; nt++) acc[mt][nt] = zero;

    int arow = tid >> 2;                              // 0..63
    int aq   = (tid & 3) ^ ((arow >> 1) & 3);         // permuted k-chunk
    const bf16*  ag0 = A  + (size_t)(bm * 128 + arow) * K + aq * 8;
    const float* bg0 = Bw + (size_t)(bn * 128 + arow) * K + aq * 8;

    // stage tile 0
    gl_lds16(ag0,                    &At[0][tid * 8]);
    gl_lds16(ag0 + (size_t)64 * K,   &At[0][2048 + tid * 8]);
    {
        f32x4 b0a = *(const f32x4*)(bg0);
        f32x4 b0b = *(const f32x4*)(bg0 + 4);
        f32x4 b1a = *(const f32x4*)(bg0 + (size_t)64 * K);
        f32x4 b1b = *(const f32x4*)(bg0 + (size_t)64 * K + 4);
        bf16x8 b0, b1;
        #pragma unroll
        for (int j = 0; j < 4; j++) {
            b0[j] = (bf16)b0a[j]; b0[4 + j] = (bf16)b0b[j];
            b1[j] = (bf16)b1a[j]; b1[4 + j] = (bf16)b1b[j];
        }
        *(bf16x8*)(&Bt[0][tid * 8])        = b0;
        *(bf16x8*)(&Bt[0][2048 + tid * 8]) = b1;
    }
    __syncthreads();

    int nk = K >> 5;
    f32x4 pba, pbb, pca, pcb;     // B prefetch registers
    for (int kt = 0; kt < nk; kt++) {
        int cur = kt & 1, nxt = cur ^ 1;
        if (kt + 1 < nk) {
            const bf16*  ag = ag0 + (size_t)(kt + 1) * 32;
            const float* bg = bg0 + (size_t)(kt + 1) * 32;
            gl_lds16(ag,                  &At[nxt][tid * 8]);
            gl_lds16(ag + (size_t)64 * K, &At[nxt][2048 + tid * 8]);
            pba = *(const f32x4*)(bg);
            pbb = *(const f32x4*)(bg + 4);
            pca = *(const f32x4*)(bg + (size_t)64 * K);
            pcb = *(const f32x4*)(bg + (size_t)64 * K + 4);
        }

        bf16x8 af[4], bfr[4];
        #pragma unroll
        for (int mt = 0; mt < 4; mt++)
            af[mt] = *(const bf16x8*)(&At[cur][wm * 2048 + (mt * 16 + l15) * 32 + ((quad ^ swz) << 3)]);
        #pragma unroll
        for (int nt = 0; nt < 4; nt++)
            bfr[nt] = *(const bf16x8*)(&Bt[cur][wn * 2048 + (nt * 16 + l15) * 32 + ((quad ^ swz) << 3)]);
        #pragma unroll
        for (int mt = 0; mt < 4; mt++)
            #pragma unroll
            for (int nt = 0; nt < 4; nt++)
                acc[mt][nt] = __builtin_amdgcn_mfma_f32_16x16x32_bf16(
                    af[mt], bfr[nt], acc[mt][nt], 0, 0, 0);

        if (kt + 1 < nk) {
            bf16x8 b0, b1;
            #pragma unroll
            for (int j = 0; j < 4; j++) {
                b0[j] = (bf16)pba[j]; b0[4 + j] = (bf16)pbb[j];
                b1[j] = (bf16)pca[j]; b1[4 + j] = (bf16)pcb[j];
            }
            *(bf16x8*)(&Bt[nxt][tid * 8])        = b0;
            *(bf16x8*)(&Bt[nxt][2048 + tid * 8]) = b1;
        }
        __syncthreads();
    }

    if (MODE == 3) {
        if (bn < 12) {
            #pragma unroll
            for (int nt = 0; nt < 4; nt++) {
                int col = bn * 128 + wn * 64 + nt * 16 + l15;
                #pragma unroll
                for (int mt = 0; mt < 4; mt++)
                    #pragma unroll
                    for (int r = 0; r < 4; r++) {
                        int row = bm * 128 + wm * 64 + mt * 16 + quad * 4 + r;
                        ((bf16*)out)[(size_t)row * 1536 + col] = (bf16)acc[mt][nt][r];
                    }
            }
        } else {
            int b = bm >> 4;
            #pragma unroll
            for (int nt = 0; nt < 4; nt++) {
                int vcol = bn * 128 - 1536 + wn * 64 + nt * 16 + l15;  // 0..767
                int h = vcol >> 6, d = vcol & 63;
                size_t rowbase = ((size_t)(b * H_ + h) * 64 + d) * N_;
                #pragma unroll
                for (int mt = 0; mt < 4; mt++) {
                    int n0 = (bm & 15) * 128 + wm * 64 + mt * 16 + quad * 4;
                    bf16x4 pv;
                    #pragma unroll
                    for (int r = 0; r < 4; r++) pv[r] = (bf16)acc[mt][nt][r];
                    *(bf16x4*)(&out2[rowbase + n0]) = pv;
                }
            }
        }
    } else {
        #pragma unroll
        for (int nt = 0; nt < 4; nt++) {
            int col = bn * 128 + wn * 64 + nt * 16 + l15;
            float bv = bias[col];
            #pragma unroll
            for (int mt = 0; mt < 4; mt++) {
                #pragma unroll
                for (int r = 0; r < 4; r++) {
                    int row = bm * 128 + wm * 64 + mt * 16 + quad * 4 + r;
                    size_t idx = (size_t)row * N + col;
                    float v = acc[mt][nt][r] + bv;
                    float ge = 0.5f * v * (1.f + erff(v * 0.70710678118f));
                    ((bf16*)out)[idx] = (bf16)ge;
                }
            }
        }
    }
}

// ---------------------------------------------------------------------------
// GEMM (narrow-N, N=768): 128x64 tile, BK=32, double-buffered, same fixed
// pipeline as gemm_bt (B prefetch held in regs across compute).
// out f32 = acc + bias + resid (resid may alias out).
// ---------------------------------------------------------------------------
__global__ __launch_bounds__(256)
void gemm64(const bf16* __restrict__ A, const float* __restrict__ Bw,
            int K, const float* __restrict__ bias,
            const float* resid_f, float* out)
{
    __shared__ bf16 At[2][128 * 32];
    __shared__ bf16 Bt[2][64 * 32];
    int tid  = threadIdx.x;
    int lane = tid & 63, wave = tid >> 6;
    int quad = lane >> 4, l15 = lane & 15;
    int bm = blockIdx.x, bn = blockIdx.y;
    int wm = wave >> 1, wn = wave & 1;
    int swz = (l15 >> 1) & 3;

    f32x4 acc[4][2];
    f32x4 zero = {0.f, 0.f, 0.f, 0.f};
    #pragma unroll
    for (int mt = 0; mt < 4; mt++)
        #pragma unroll
        for (int nt = 0; nt < 2; nt++) acc[mt][nt] = zero;

    int arow = tid >> 2;                              // 0..63
    int aq   = (tid & 3) ^ ((arow >> 1) & 3);         // permuted k-chunk
    const bf16*  ag0 = A  + (size_t)(bm * 128 + arow) * K + aq * 8;
    const float* bg0 = Bw + (size_t)(bn * 64  + arow) * K + aq * 8;

    // stage tile 0
    gl_lds16(ag0,                  &At[0][tid * 8]);
    gl_lds16(ag0 + (size_t)64 * K, &At[0][2048 + tid * 8]);
    {
        f32x4 ba = *(const f32x4*)(bg0);
        f32x4 bb = *(const f32x4*)(bg0 + 4);
        bf16x8 b0;
        #pragma unroll
        for (int j = 0; j < 4; j++) { b0[j] = (bf16)ba[j]; b0[4 + j] = (bf16)bb[j]; }
        *(bf16x8*)(&Bt[0][tid * 8]) = b0;
    }
    __syncthreads();

    int nk = K >> 5;
    f32x4 pba, pbb;
    for (int kt = 0; kt < nk; kt++) {
        int cur = kt & 1, nxt = cur ^ 1;
        if (kt + 1 < nk) {
            const bf16*  ag = ag0 + (size_t)(kt + 1) * 32;
            const float* bg = bg0 + (size_t)(kt + 1) * 32;
            gl_lds16(ag,                  &At[nxt][tid * 8]);
            gl_lds16(ag + (size_t)64 * K, &At[nxt][2048 + tid * 8]);
            pba = *(const f32x4*)(bg);
            pbb = *(const f32x4*)(bg + 4);
        }

        bf16x8 af[4], bfr[2];
        #pragma unroll
        for (int mt = 0; mt < 4; mt++)
            af[mt] = *(const bf16x8*)(&At[cur][wm * 2048 + (mt * 16 + l15) * 32 + ((quad ^ swz) << 3)]);
        #pragma unroll
        for (int nt = 0; nt < 2; nt++)
            bfr[nt] = *(const bf16x8*)(&Bt[cur][(wn * 32 + nt * 16 + l15) * 32 + ((quad ^ swz) << 3)]);
        #pragma unroll
        for (int mt = 0; mt < 4; mt++)
            #pragma unroll
            for (int nt = 0; nt < 2; nt++)
                acc[mt][nt] = __builtin_amdgcn_mfma_f32_16x16x32_bf16(
                    af[mt], bfr[nt], acc[mt][nt], 0, 0, 0);

        if (kt + 1 < nk) {
            bf16x8 b0;
            #pragma unroll
            for (int j = 0; j < 4; j++) { b0[j] = (bf16)pba[j]; b0[4 + j] = (bf16)pbb[j]; }
            *(bf16x8*)(&Bt[nxt][tid * 8]) = b0;
        }
        __syncthreads();
    }

    #pragma unroll
    for (int nt = 0; nt < 2; nt++) {
        int col = bn * 64 + wn * 32 + nt * 16 + l15;
        float bv = bias[col];
        #pragma unroll
        for (int mt = 0; mt < 4; mt++) {
            #pragma unroll
            for (int r = 0; r < 4; r++) {
                int row = bm * 128 + wm * 64 + mt * 16 + quad * 4 + r;
                size_t idx = (size_t)row * C_ + col;
                out[idx] = acc[mt][nt][r] + bv + resid_f[idx];
            }
        }
    }
}

// ---------------------------------------------------------------------------
// Flash attention, transposed formulation (unchanged from round 5).
// ---------------------------------------------------------------------------
__global__ __launch_bounds__(256)
void attn_kernel(const bf16* __restrict__ qk, const bf16* __restrict__ vt,
                 bf16* __restrict__ o)
{
    __shared__ bf16 Kt[2][64 * 64];     // [key][d], swizzled
    __shared__ bf16 Vt[2][64 * 64];     // [d][key], swizzled
    __shared__ bf16 Pt[4][2][16 * 64];  // per-wave, per-qtile [query][key], swizzled

    int tid = threadIdx.x, lane = tid & 63, wave = tid >> 6;
    int quad = lane >> 4, l15 = lane & 15;
    int swz = (l15 & 7);                // read-side swizzle key
    int blk = blockIdx.x;
    int qb = blk & 15;      // 16 query blocks of 128
    int bh = blk >> 4;      // 0..47
    int b = bh / H_, h = bh % H_;

    const bf16* qbase = qk + (size_t)(b * N_) * 1536 + h * 64;
    const bf16* kbase = qbase + 768;
    const bf16* vtb   = vt + (size_t)(bh * 64) * N_;

    bf16x8 qf[2][2];
    #pragma unroll
    for (int qi = 0; qi < 2; qi++) {
        int q = qb * 128 + wave * 32 + qi * 16 + l15;
        const bf16* qp = qbase + (size_t)q * 1536 + quad * 8;
        qf[qi][0] = *(const bf16x8*)(qp);
        qf[qi][1] = *(const bf16x8*)(qp + 32);
    }

    int srow = tid >> 3, schk = tid & 7;
    int soA = srow * 64 + ((schk ^ (srow & 7)) << 3);
    int soB = (srow + 32) * 64 + ((schk ^ (srow & 7)) << 3);

    bf16x8 kr0, kr1, vr0, vr1;
    const bf16* kg0 = kbase + (size_t)srow * 1536 + schk * 8;
    const bf16* vg0 = vtb + (size_t)srow * N_ + schk * 8;

    {
        kr0 = *(const bf16x8*)(kg0);
        kr1 = *(const bf16x8*)(kg0 + (size_t)32 * 1536);
        vr0 = *(const bf16x8*)(vg0);
        vr1 = *(const bf16x8*)(vg0 + (size_t)32 * N_);
        *(bf16x8*)(&Kt[0][soA]) = kr0;  *(bf16x8*)(&Kt[0][soB]) = kr1;
        *(bf16x8*)(&Vt[0][soA]) = vr0;  *(bf16x8*)(&Vt[0][soB]) = vr1;
    }
    __syncthreads();

    f32x4 oacc[2][4];
    f32x4 zero = {0.f, 0.f, 0.f, 0.f};
    #pragma unroll
    for (int qi = 0; qi < 2; qi++)
        #pragma unroll
        for (int nt = 0; nt < 4; nt++) oacc[qi][nt] = zero;
    float mrun[2] = {-1e30f, -1e30f}, lrun[2] = {0.f, 0.f};

    for (int kt = 0; kt < 32; kt++) {
        int cur = kt & 1;
        if (kt < 31) {
            const bf16* kg = kg0 + (size_t)(kt + 1) * 64 * 1536;
            const bf16* vg = vg0 + (size_t)(kt + 1) * 64;
            kr0 = *(const bf16x8*)(kg);
            kr1 = *(const bf16x8*)(kg + (size_t)32 * 1536);
            vr0 = *(const bf16x8*)(vg);
            vr1 = *(const bf16x8*)(vg + (size_t)32 * N_);
        }
        const bf16* KtC = &Kt[cur][0];
        const bf16* VtC = &Vt[cur][0];

        #pragma unroll
        for (int qi = 0; qi < 2; qi++) {
            f32x4 s[4];
            #pragma unroll
            for (int nt = 0; nt < 4; nt++) {
                const bf16* krow = KtC + (nt * 16 + l15) * 64;
                bf16x8 ka0 = *(const bf16x8*)(krow + ((quad ^ swz) << 3));
                bf16x8 ka1 = *(const bf16x8*)(krow + (((4 + quad) ^ swz) << 3));
                f32x4 sv = zero;
                sv = __builtin_amdgcn_mfma_f32_16x16x32_bf16(ka0, qf[qi][0], sv, 0, 0, 0);
                sv = __builtin_amdgcn_mfma_f32_16x16x32_bf16(ka1, qf[qi][1], sv, 0, 0, 0);
                s[nt] = sv;
            }
            float mx = -1e30f;
            #pragma unroll
            for (int nt = 0; nt < 4; nt++)
                #pragma unroll
                for (int r = 0; r < 4; r++) mx = fmaxf(mx, s[nt][r]);
            mx = fmaxf(mx, __shfl_xor(mx, 16, 64));
            mx = fmaxf(mx, __shfl_xor(mx, 32, 64));
            float mnew = fmaxf(mrun[qi], mx * 0.125f);
            float al   = __expf(mrun[qi] - mnew);
            mrun[qi] = mnew;
            float ps = 0.f;
            #pragma unroll
            for (int nt = 0; nt < 4; nt++)
                #pragma unroll
                for (int r = 0; r < 4; r++) {
                    float pv = __expf(s[nt][r] * 0.125f - mnew);
                    s[nt][r] = pv;
                    ps += pv;
                }
            ps += __shfl_xor(ps, 16, 64);
            ps += __shfl_xor(ps, 32, 64);
            lrun[qi] = lrun[qi] * al + ps;
            #pragma unroll
            for (int nt = 0; nt < 4; nt++) oacc[qi][nt] *= al;
            bf16* pw = &Pt[wave][qi][0];
            #pragma unroll
            for (int nt = 0; nt < 4; nt++) {
                bf16x4 pk;
                #pragma unroll
                for (int r = 0; r < 4; r++) pk[r] = (bf16)s[nt][r];
                int ofs = l15 * 64 + (((nt * 2 + (quad >> 1)) ^ swz) << 3) + ((quad & 1) << 2);
                *(bf16x4*)(&pw[ofs]) = pk;
            }
        }

        #pragma unroll
        for (int kc = 0; kc < 2; kc++) {
            int pofs = l15 * 64 + (((kc * 4 + quad) ^ swz) << 3);
            bf16x8 pb0 = *(const bf16x8*)(&Pt[wave][0][pofs]);
            bf16x8 pb1 = *(const bf16x8*)(&Pt[wave][1][pofs]);
            #pragma unroll
            for (int nt = 0; nt < 4; nt++) {
                bf16x8 va = *(const bf16x8*)(VtC + (nt * 16 + l15) * 64 +
                                             (((kc * 4 + quad) ^ swz) << 3));
                oacc[0][nt] = __builtin_amdgcn_mfma_f32_16x16x32_bf16(va, pb0, oacc[0][nt], 0, 0, 0);
                oacc[1][nt] = __builtin_amdgcn_mfma_f32_16x16x32_bf16(va, pb1, oacc[1][nt], 0, 0, 0);
            }
        }

        if (kt < 31) {
            int nxt = cur ^ 1;
            *(bf16x8*)(&Kt[nxt][soA]) = kr0;  *(bf16x8*)(&Kt[nxt][soB]) = kr1;
            *(bf16x8*)(&Vt[nxt][soA]) = vr0;  *(bf16x8*)(&Vt[nxt][soB]) = vr1;
        }
        __syncthreads();
    }

    #pragma unroll
    for (int qi = 0; qi < 2; qi++) {
        int q = qb * 128 + wave * 32 + qi * 16 + l15;
        float inv = 1.f / lrun[qi];
        bf16* ob = o + (size_t)(b * N_ + q) * C_ + h * 64 + quad * 4;
        #pragma unroll
        for (int nt = 0; nt < 4; nt++) {
            bf16x4 pk;
            #pragma unroll
            for (int r = 0; r < 4; r++) pk[r] = (bf16)(oacc[qi][nt][r] * inv);
            *(bf16x4*)(&ob[nt * 16]) = pk;
        }
    }
}

// ---------------------------------------------------------------------------
// Workspace (62.9 MB):
//   [0, 25165824)          QK [T,1536] bf16      (attention phase)
//   [25165824, 37748736)   V_T [48][64][2048] bf16
//   [0, 50331648)          gelu(fc1) [T,3072] bf16 (MLP phase, reuses above)
//   [50331648, 62914560)   R1: h / o / h2 [T,768] bf16
// Residual stream x1 lives f32 in d_out.
// ---------------------------------------------------------------------------
extern "C" void kernel_launch(void* const* d_in, const int* in_sizes, int n_in,
                              void* d_out, int out_size, void* d_ws, size_t ws_size,
                              hipStream_t stream)
{
    const float* x      = (const float*)d_in[0];
    const float* ln1_g  = (const float*)d_in[1];
    const float* ln1_b  = (const float*)d_in[2];
    const float* qkv_w  = (const float*)d_in[3];
    const float* proj_w = (const float*)d_in[4];
    const float* proj_b = (const float*)d_in[5];
    const float* ln2_g  = (const float*)d_in[6];
    const float* ln2_b  = (const float*)d_in[7];
    const float* fc1_w  = (const float*)d_in[8];
    const float* fc1_b  = (const float*)d_in[9];
    const float* fc2_w  = (const float*)d_in[10];
    const float* fc2_b  = (const float*)d_in[11];
    float* out = (float*)d_out;

    char* ws = (char*)d_ws;
    bf16* QK = (bf16*)ws;                                   // T x 1536
    bf16* VT = (bf16*)(ws + (size_t)T_ * 1536 * 2);         // 48 x 64 x 2048
    bf16* G  = (bf16*)ws;                                   // T x 3072 (MLP phase)
    bf16* R1 = (bf16*)(ws + (size_t)T_ * HID_ * 2);         // T x 768

    // 1. LN1: x (f32) -> h (R1, bf16)
    ln_kernel<<<T_ / 4, 256, 0, stream>>>(x, ln1_g, ln1_b, R1);
    // 2. qkv = h @ qkv_w^T -> QK [T,1536] + VT (transposed V)
    gemm_bt<3><<<dim3(T_ / 128, 2304 / 128), 256, 0, stream>>>(
        R1, qkv_w, T_, 2304, C_, nullptr, QK, VT);
    // 3. attention -> o (R1) [T,768] bf16
    attn_kernel<<<48 * 16, 256, 0, stream>>>(QK, VT, R1);
    // 4. x1 = x + o @ proj_w^T + proj_b -> d_out (f32)
    gemm64<<<dim3(T_ / 128, C_ / 64), 256, 0, stream>>>(
        R1, proj_w, C_, proj_b, x, out);
    // 5. LN2: x1 (f32) -> h2 (R1, bf16)
    ln_kernel<<<T_ / 4, 256, 0, stream>>>(out, ln2_g, ln2_b, R1);
    // 6. g1 = gelu(h2 @ fc1_w^T + fc1_b) -> G [T,3072] bf16
    gemm_bt<2><<<dim3(T_ / 128, HID_ / 128), 256, 0, stream>>>(
        R1, fc1_w, T_, HID_, C_, fc1_b, G, nullptr);
    // 7. out = x1 + g1 @ fc2_w^T + fc2_b -> d_out (in-place residual read, f32)
    gemm64<<<dim3(T_ / 128, C_ / 64), 256, 0, stream>>>(
        G, fc2_w, HID_, fc2_b, out, out);
}